// Round 2
// baseline (1581.271 us; speedup 1.0000x reference)
//
#include <hip/hip_runtime.h>
#include <hip/hip_bf16.h>
#include <math.h>

typedef __hip_bfloat16 bf16;

// Problem constants (DocREModel)
constexpr int B = 4, H = 12, C = 1024, D = 768, E = 30, M = 8, P = 600;
constexpr int NL = 97, RELS = 96, EMB = 768;
constexpr int N = B * P;          // 2400 pairs
constexpr int KHEAD = 2 * D;      // 1536
constexpr int KB_BLOCKS = 12;     // EMB/64 k-blocks in bilinear

static __device__ __forceinline__ float b2f(bf16 x) { return __bfloat162float(x); }

// dtype-agnostic load/store: BF=true -> buffer holds bf16, else float32
template <bool BF>
static __device__ __forceinline__ float ldf(const void* p, size_t i) {
  if (BF) return b2f(((const bf16*)p)[i]);
  return ((const float*)p)[i];
}
template <bool BF>
static __device__ __forceinline__ void stf(void* p, size_t i, float v) {
  if (BF) ((bf16*)p)[i] = __float2bfloat16(v);
  else    ((float*)p)[i] = v;
}

// ---------------------------------------------------------------------------
// Kernel 0: detect input dtype from mention_mask bit patterns.
// f32 mode: words are only 0x00000000 / 0x3F800000.
// bf16 mode: each entity's first word is 0x00003F80 or 0x3F803F80 (impossible
// in f32 mode). mm has >=480 words in both modes.
// ---------------------------------------------------------------------------
__global__ __launch_bounds__(256) void k_detect(const unsigned int* __restrict__ mm,
                                                int* __restrict__ flag) {
  __shared__ int found;
  if (threadIdx.x == 0) found = 0;
  __syncthreads();
  for (int i = threadIdx.x; i < 480; i += 256) {
    unsigned int w = mm[i];
    if (w == 0x00003F80u || w == 0x3F803F80u) found = 1;
  }
  __syncthreads();
  if (threadIdx.x == 0) *flag = found;
}

// ---------------------------------------------------------------------------
// Kernel 1: ent_emb[b,e,d] = logsumexp over masked mentions of seq[b, idx, d]
// ---------------------------------------------------------------------------
struct EntEmbSmem { int sidx[M]; float smask[M]; };

template <bool BF>
static __device__ __forceinline__ void ent_emb_body(
    EntEmbSmem& s, const void* seq, const int* midx, const void* mmask,
    float* ent_emb) {
  int be = blockIdx.x;
  int b = be / E;
  if (threadIdx.x < M) {
    s.sidx[threadIdx.x] = midx[be * M + threadIdx.x] + 1;  // OFFSET
    s.smask[threadIdx.x] = ldf<BF>(mmask, be * M + threadIdx.x);
  }
  __syncthreads();
  for (int d = threadIdx.x; d < D; d += 256) {
    float v[M];
    float mx = -1e30f;
#pragma unroll
    for (int m = 0; m < M; m++) {
      v[m] = ldf<BF>(seq, ((size_t)(b * C + s.sidx[m])) * D + d);
      if (s.smask[m] != 0.0f) mx = fmaxf(mx, v[m]);
    }
    float sum = 0.f;
#pragma unroll
    for (int m = 0; m < M; m++)
      if (s.smask[m] != 0.0f) sum += expf(v[m] - mx);
    ent_emb[(size_t)be * D + d] = logf(sum) + mx;
  }
}

__global__ __launch_bounds__(256) void k_ent_emb(
    const void* seq, const int* midx, const void* mmask, float* ent_emb,
    const int* flag) {
  __shared__ EntEmbSmem s;
  if (*flag) ent_emb_body<true>(s, seq, midx, mmask, ent_emb);
  else       ent_emb_body<false>(s, seq, midx, mmask, ent_emb);
}

// ---------------------------------------------------------------------------
// Kernel 2: ent_att[b,e,h,c] = (sum_m mask*att[b,h,idx,c]) / cnt
// ---------------------------------------------------------------------------
struct EntAttSmem { int sidx[M]; float smask[M]; float sinv; };

template <bool BF>
static __device__ __forceinline__ void ent_att_body(
    EntAttSmem& s, const void* att, const int* midx, const void* mmask,
    float* ent_att) {
  int beh = blockIdx.x;
  int h = beh % H;
  int be = beh / H;
  int b = be / E;
  if (threadIdx.x < M) {
    s.sidx[threadIdx.x] = midx[be * M + threadIdx.x] + 1;
    s.smask[threadIdx.x] = ldf<BF>(mmask, be * M + threadIdx.x);
  }
  __syncthreads();
  if (threadIdx.x == 0) {
    float cnt = 0.f;
    for (int m = 0; m < M; m++) cnt += s.smask[m];
    s.sinv = 1.0f / cnt;
  }
  __syncthreads();
  for (int c = threadIdx.x; c < C; c += 256) {
    float sum = 0.f;
#pragma unroll
    for (int m = 0; m < M; m++)
      if (s.smask[m] != 0.0f)
        sum += ldf<BF>(att, (((size_t)b * H + h) * C + s.sidx[m]) * C + c);
    ent_att[((size_t)be * H + h) * C + c] = sum * s.sinv;
  }
}

__global__ __launch_bounds__(256) void k_ent_att(
    const void* att, const int* midx, const void* mmask, float* ent_att,
    const int* flag) {
  __shared__ EntAttSmem s;
  if (*flag) ent_att_body<true>(s, att, midx, mmask, ent_att);
  else       ent_att_body<false>(s, att, midx, mmask, ent_att);
}

// ---------------------------------------------------------------------------
// Kernel 3: ht_att[b,p,c] = normalize_c( mean_h( eA[h_i]*eA[t_i] ) )
// (reads only f32 workspace — no dtype branch needed)
// ---------------------------------------------------------------------------
__global__ __launch_bounds__(256) void k_ht_att(
    const float* __restrict__ ent_att, const int* __restrict__ hts,
    float* __restrict__ ht_att) {
  int bp = blockIdx.x;
  int b = bp / P;
  int hi = hts[bp * 2 + 0], ti = hts[bp * 2 + 1];
  const float* hA = ent_att + ((size_t)(b * E + hi)) * H * C;
  const float* tA = ent_att + ((size_t)(b * E + ti)) * H * C;
  float v[4];
  float loc = 0.f;
#pragma unroll
  for (int q = 0; q < 4; q++) {
    int c = threadIdx.x + q * 256;
    float s = 0.f;
#pragma unroll
    for (int h = 0; h < H; h++) s += hA[h * C + c] * tA[h * C + c];
    v[q] = s * (1.0f / H);
    loc += v[q];
  }
  __shared__ float red[256];
  red[threadIdx.x] = loc;
  __syncthreads();
  for (int off = 128; off > 0; off >>= 1) {
    if (threadIdx.x < off) red[threadIdx.x] += red[threadIdx.x + off];
    __syncthreads();
  }
  float inv = 1.0f / (red[0] + 1e-5f);
#pragma unroll
  for (int q = 0; q < 4; q++) {
    int c = threadIdx.x + q * 256;
    ht_att[(size_t)bp * C + c] = v[q] * inv;
  }
}

// ---------------------------------------------------------------------------
// Kernel 4: rs[b] = ht_att[b] (600x1024) @ seq[b] (1024x768)
// ---------------------------------------------------------------------------
struct GemmSmem { float At[64][33]; float Bt[32][64]; };

template <bool BF>
static __device__ __forceinline__ void rs_body(
    GemmSmem& s, const float* ht_att, const void* seq, float* rs) {
  int b = blockIdx.z;
  int r0 = blockIdx.x * 64;
  int c0 = blockIdx.y * 64;
  float acc[4][4] = {};
  int t = threadIdx.x;
  int ty = t / 16, tx = t % 16;
  for (int kt = 0; kt < C; kt += 32) {
#pragma unroll
    for (int l = 0; l < 8; l++) {
      int e = t + l * 256;
      int r = e / 32, kk = e % 32;
      int p = r0 + r;
      s.At[r][kk] = (p < P) ? ht_att[((size_t)b * P + p) * C + kt + kk] : 0.f;
    }
#pragma unroll
    for (int l = 0; l < 8; l++) {
      int e = t + l * 256;
      int kk = e / 64, cc = e % 64;
      s.Bt[kk][cc] = ldf<BF>(seq, ((size_t)b * C + kt + kk) * D + c0 + cc);
    }
    __syncthreads();
#pragma unroll
    for (int kk = 0; kk < 32; kk++) {
      float a0 = s.At[ty * 4 + 0][kk], a1 = s.At[ty * 4 + 1][kk];
      float a2 = s.At[ty * 4 + 2][kk], a3 = s.At[ty * 4 + 3][kk];
      float4 bv = *(const float4*)(&s.Bt[kk][tx * 4]);
      acc[0][0] += a0 * bv.x; acc[0][1] += a0 * bv.y; acc[0][2] += a0 * bv.z; acc[0][3] += a0 * bv.w;
      acc[1][0] += a1 * bv.x; acc[1][1] += a1 * bv.y; acc[1][2] += a1 * bv.z; acc[1][3] += a1 * bv.w;
      acc[2][0] += a2 * bv.x; acc[2][1] += a2 * bv.y; acc[2][2] += a2 * bv.z; acc[2][3] += a2 * bv.w;
      acc[3][0] += a3 * bv.x; acc[3][1] += a3 * bv.y; acc[3][2] += a3 * bv.z; acc[3][3] += a3 * bv.w;
    }
    __syncthreads();
  }
#pragma unroll
  for (int i = 0; i < 4; i++) {
    int p = r0 + ty * 4 + i;
    if (p < P) {
#pragma unroll
      for (int j = 0; j < 4; j++)
        rs[((size_t)b * P + p) * D + c0 + tx * 4 + j] = acc[i][j];
    }
  }
}

__global__ __launch_bounds__(256) void k_rs(
    const float* ht_att, const void* seq, float* rs, const int* flag) {
  __shared__ GemmSmem s;
  if (*flag) rs_body<true>(s, ht_att, seq, rs);
  else       rs_body<false>(s, ht_att, seq, rs);
}

// ---------------------------------------------------------------------------
// Kernel 5: hz/tz = tanh([hs|ts, rs] @ {head,tail}_W + bias)
// ---------------------------------------------------------------------------
struct HeadSmem { float At[64][33]; float Bt[32][64]; int ebase[64]; };

template <bool BF>
static __device__ __forceinline__ void head_body(
    HeadSmem& s, const float* ent_emb, const float* rs, const int* hts,
    const void* headW, const void* headb, const void* tailW, const void* tailb,
    float* hz, float* tz) {
  int which = blockIdx.z;
  const void* W = which ? tailW : headW;
  const void* bias = which ? tailb : headb;
  float* out = which ? tz : hz;
  int r0 = blockIdx.x * 64, c0 = blockIdx.y * 64;
  int t = threadIdx.x;
  if (t < 64) {
    int n = r0 + t;
    int nn = (n < N) ? n : 0;
    int b = nn / P, p = nn % P;
    int e = hts[(b * P + p) * 2 + which];
    s.ebase[t] = (b * E + e) * D;
  }
  __syncthreads();
  float acc[4][4] = {};
  int ty = t / 16, tx = t % 16;
  for (int kt = 0; kt < KHEAD; kt += 32) {
#pragma unroll
    for (int l = 0; l < 8; l++) {
      int e = t + l * 256;
      int r = e / 32, kk = e % 32;
      int n = r0 + r;
      int k = kt + kk;
      float v = 0.f;
      if (n < N) {
        if (k < D) v = ent_emb[s.ebase[r] + k];
        else       v = rs[(size_t)n * D + (k - D)];
      }
      s.At[r][kk] = v;
    }
#pragma unroll
    for (int l = 0; l < 8; l++) {
      int e = t + l * 256;
      int kk = e / 64, cc = e % 64;
      s.Bt[kk][cc] = ldf<BF>(W, (size_t)(kt + kk) * EMB + c0 + cc);
    }
    __syncthreads();
#pragma unroll
    for (int kk = 0; kk < 32; kk++) {
      float a0 = s.At[ty * 4 + 0][kk], a1 = s.At[ty * 4 + 1][kk];
      float a2 = s.At[ty * 4 + 2][kk], a3 = s.At[ty * 4 + 3][kk];
      float4 bv = *(const float4*)(&s.Bt[kk][tx * 4]);
      acc[0][0] += a0 * bv.x; acc[0][1] += a0 * bv.y; acc[0][2] += a0 * bv.z; acc[0][3] += a0 * bv.w;
      acc[1][0] += a1 * bv.x; acc[1][1] += a1 * bv.y; acc[1][2] += a1 * bv.z; acc[1][3] += a1 * bv.w;
      acc[2][0] += a2 * bv.x; acc[2][1] += a2 * bv.y; acc[2][2] += a2 * bv.z; acc[2][3] += a2 * bv.w;
      acc[3][0] += a3 * bv.x; acc[3][1] += a3 * bv.y; acc[3][2] += a3 * bv.z; acc[3][3] += a3 * bv.w;
    }
    __syncthreads();
  }
#pragma unroll
  for (int i = 0; i < 4; i++) {
    int n = r0 + ty * 4 + i;
    if (n < N) {
#pragma unroll
      for (int j = 0; j < 4; j++) {
        int cc = c0 + tx * 4 + j;
        out[(size_t)n * EMB + cc] = tanhf(acc[i][j] + ldf<BF>(bias, cc));
      }
    }
  }
}

__global__ __launch_bounds__(256) void k_head(
    const float* ent_emb, const float* rs, const int* hts,
    const void* headW, const void* headb, const void* tailW, const void* tailb,
    float* hz, float* tz, const int* flag) {
  __shared__ HeadSmem s;
  if (*flag) head_body<true>(s, ent_emb, rs, hts, headW, headb, tailW, tailb, hz, tz);
  else       head_body<false>(s, ent_emb, rs, hts, headW, headb, tailW, tailb, hz, tz);
}

// ---------------------------------------------------------------------------
// Kernel 6: logits partials. bl[n, k*4096+i*64+j] = hz[n,k*64+i]*tz[n,k*64+j]
// part[kb][n][l] = partial logits for k-block kb. A generated on the fly.
// ---------------------------------------------------------------------------
struct LogitsSmem { float HZ[64][68]; float TZ[64][68]; float Wt[64][100]; };

template <bool BF>
static __device__ __forceinline__ void logits_body(
    LogitsSmem& s, const float* hz, const float* tz, const void* bilW,
    float* part) {
  int rb = blockIdx.x, kb = blockIdx.y;
  int r0 = rb * 64;
  int t = threadIdx.x;
#pragma unroll
  for (int l = 0; l < 16; l++) {
    int e = t + l * 256;
    int kk = e % 64, r = e / 64;
    int n = r0 + r;
    float hv = 0.f, tv = 0.f;
    if (n < N) {
      hv = hz[(size_t)n * EMB + kb * 64 + kk];
      tv = tz[(size_t)n * EMB + kb * 64 + kk];
    }
    s.HZ[kk][r] = hv;
    s.TZ[kk][r] = tv;
  }
  float acc[4][7] = {};
  int ty = t / 16, tx = t % 16;
  __syncthreads();
  for (int i = 0; i < 64; i++) {
    const size_t wbase = ((size_t)kb * 4096 + (size_t)i * 64) * NL;
    for (int e = t; e < 64 * NL; e += 256) {
      int j = e / NL, l = e % NL;
      s.Wt[j][l] = ldf<BF>(bilW, wbase + e);
    }
    __syncthreads();
    float4 hv = *(const float4*)(&s.HZ[i][ty * 4]);
#pragma unroll 8
    for (int j = 0; j < 64; j++) {
      float4 tv = *(const float4*)(&s.TZ[j][ty * 4]);
      float a0 = hv.x * tv.x, a1 = hv.y * tv.y, a2 = hv.z * tv.z, a3 = hv.w * tv.w;
      float wv[7];
#pragma unroll
      for (int q = 0; q < 7; q++) {
        int l = tx + 16 * q;
        wv[q] = (l < NL) ? s.Wt[j][l] : 0.f;
      }
#pragma unroll
      for (int q = 0; q < 7; q++) {
        acc[0][q] += a0 * wv[q];
        acc[1][q] += a1 * wv[q];
        acc[2][q] += a2 * wv[q];
        acc[3][q] += a3 * wv[q];
      }
    }
    __syncthreads();
  }
  float* pp = part + (size_t)kb * N * NL;
#pragma unroll
  for (int rr = 0; rr < 4; rr++) {
    int n = r0 + ty * 4 + rr;
    if (n < N) {
#pragma unroll
      for (int q = 0; q < 7; q++) {
        int l = tx + 16 * q;
        if (l < NL) pp[(size_t)n * NL + l] = acc[rr][q];
      }
    }
  }
}

__global__ __launch_bounds__(256) void k_logits(
    const float* hz, const float* tz, const void* bilW, float* part,
    const int* flag) {
  __shared__ LogitsSmem s;
  if (*flag) logits_body<true>(s, hz, tz, bilW, part);
  else       logits_body<false>(s, hz, tz, bilW, part);
}

// ---------------------------------------------------------------------------
// Kernel 6b: logits[n,l] = sum_kb part + bias; write f32 (ws) and out (dtype)
// ---------------------------------------------------------------------------
template <bool BF>
static __device__ __forceinline__ void logits_reduce_body(
    const float* part, const void* bilb, float* logits_f, void* out) {
  int idx = blockIdx.x * 256 + threadIdx.x;
  if (idx >= N * NL) return;
  int l = idx % NL;
  float s = ldf<BF>(bilb, l);
#pragma unroll
  for (int kb = 0; kb < KB_BLOCKS; kb++) s += part[(size_t)kb * N * NL + idx];
  logits_f[idx] = s;
  stf<BF>(out, (size_t)idx + 1, s);  // out[0] = risk, out[1..] = logits
}

__global__ __launch_bounds__(256) void k_logits_reduce(
    const float* part, const void* bilb, float* logits_f, void* out,
    const int* flag) {
  if (*flag) logits_reduce_body<true>(part, bilb, logits_f, out);
  else       logits_reduce_body<false>(part, bilb, logits_f, out);
}

// ---------------------------------------------------------------------------
// Kernel 7: per-relation PU risk. grid = RELS blocks.
// ---------------------------------------------------------------------------
struct RiskSmem { float red[5][256]; };

template <bool BF>
static __device__ __forceinline__ void risk_body(
    RiskSmem& sm, const float* logits_f, const int* labels,
    const void* priors_l, const void* priors_o, float* riskarr) {
  int r = blockIdx.x;  // 0..95
  int t = threadIdx.x;
  float s_neg = 0.f, s_pp = 0.f, s_pn = 0.f, c_neg = 0.f, c_pos = 0.f;
  for (int n = t; n < N; n += 256) {
    float sc = logits_f[(size_t)n * NL + (r + 1)] - logits_f[(size_t)n * NL];
    bool pos = labels[(size_t)n * NL + (r + 1)] == 1;
    float ln = 0.25f * (sc + 1.f) * (sc + 1.f);  // sign=-1
    float lp = 0.25f * (sc - 1.f) * (sc - 1.f);  // sign=+1
    if (pos) { c_pos += 1.f; s_pp += lp; s_pn += ln; }
    else     { c_neg += 1.f; s_neg += ln; }
  }
  sm.red[0][t] = s_neg; sm.red[1][t] = s_pp; sm.red[2][t] = s_pn;
  sm.red[3][t] = c_neg; sm.red[4][t] = c_pos;
  __syncthreads();
  for (int off = 128; off > 0; off >>= 1) {
    if (t < off) {
#pragma unroll
      for (int q = 0; q < 5; q++) sm.red[q][t] += sm.red[q][t + off];
    }
    __syncthreads();
  }
  if (t == 0) {
    float sq_neg   = sm.red[3][0] > 0.f ? sm.red[0][0] / fmaxf(sm.red[3][0], 1.f) : 0.f;
    float sq_pos_p = sm.red[4][0] > 0.f ? sm.red[1][0] / fmaxf(sm.red[4][0], 1.f) : 0.f;
    float sq_pos_n = sm.red[4][0] > 0.f ? sm.red[2][0] / fmaxf(sm.red[4][0], 1.f) : 0.f;
    float po = ldf<BF>(priors_o, r), pl = ldf<BF>(priors_l, r);
    float weight = sqrtf((1.f - po) / po);
    float pu = (po - pl) / (1.f - pl);
    float risk1 = (1.f - po) / (1.f - pu) * sq_neg - (pu - pu * po) / (1.f - pu) * sq_pos_n;
    float risk2 = po * sq_pos_p * weight;
    riskarr[r] = (risk1 < 0.f) ? -risk1 : (risk1 + risk2);  // BETA=0, GAMMA=1
  }
}

__global__ __launch_bounds__(256) void k_risk(
    const float* logits_f, const int* labels, const void* priors_l,
    const void* priors_o, float* riskarr, const int* flag) {
  __shared__ RiskSmem sm;
  if (*flag) risk_body<true>(sm, logits_f, labels, priors_l, priors_o, riskarr);
  else       risk_body<false>(sm, logits_f, labels, priors_l, priors_o, riskarr);
}

__global__ __launch_bounds__(128) void k_risk_sum(
    const float* __restrict__ riskarr, void* out, const int* flag) {
  __shared__ float red[128];
  int t = threadIdx.x;
  red[t] = (t < RELS) ? riskarr[t] : 0.f;
  __syncthreads();
  for (int off = 64; off > 0; off >>= 1) {
    if (t < off) red[t] += red[t + off];
    __syncthreads();
  }
  if (t == 0) {
    if (*flag) stf<true>(out, 0, red[0]);
    else       stf<false>(out, 0, red[0]);
  }
}

// ---------------------------------------------------------------------------
extern "C" void kernel_launch(void* const* d_in, const int* in_sizes, int n_in,
                              void* d_out, int out_size, void* d_ws, size_t ws_size,
                              hipStream_t stream) {
  const void* seq    = d_in[0];
  const void* att    = d_in[1];
  const int*  midx   = (const int*)d_in[2];
  const void* mmask  = d_in[3];
  const int*  hts    = (const int*)d_in[4];
  const int*  labels = (const int*)d_in[5];
  const void* pl     = d_in[6];
  const void* po     = d_in[7];
  const void* headW  = d_in[8];
  const void* headb  = d_in[9];
  const void* tailW  = d_in[10];
  const void* tailb  = d_in[11];
  const void* bilW   = d_in[12];
  const void* bilb   = d_in[13];

  // workspace layout: flag (64B), then floats; part aliases ent_att+ht_att
  int* flag = (int*)d_ws;
  float* w = (float*)d_ws + 16;
  float* ent_emb = w;                                   //  92160
  float* ent_att = w + (size_t)B * E * D;               // 1474560
  float* ht_att  = ent_att + (size_t)B * E * H * C;     // 2457600
  float* part    = ent_att;                             // 12*N*NL = 2793600 (alias)
  float* rs      = ht_att + (size_t)N * C;              // N*D
  float* hz      = rs + (size_t)N * D;                  // N*EMB
  float* tz      = hz + (size_t)N * EMB;                // N*EMB
  float* logits_f = tz + (size_t)N * EMB;               // N*NL
  float* riskarr  = logits_f + (size_t)N * NL;          // RELS

  k_detect<<<1, 256, 0, stream>>>((const unsigned int*)mmask, flag);
  k_ent_emb<<<B * E, 256, 0, stream>>>(seq, midx, mmask, ent_emb, flag);
  k_ent_att<<<B * E * H, 256, 0, stream>>>(att, midx, mmask, ent_att, flag);
  k_ht_att<<<B * P, 256, 0, stream>>>(ent_att, hts, ht_att);
  k_rs<<<dim3((P + 63) / 64, D / 64, B), 256, 0, stream>>>(ht_att, seq, rs, flag);
  k_head<<<dim3((N + 63) / 64, EMB / 64, 2), 256, 0, stream>>>(
      ent_emb, rs, hts, headW, headb, tailW, tailb, hz, tz, flag);
  k_logits<<<dim3((N + 63) / 64, KB_BLOCKS), 256, 0, stream>>>(hz, tz, bilW, part, flag);
  k_logits_reduce<<<(N * NL + 255) / 256, 256, 0, stream>>>(part, bilb, logits_f, d_out, flag);
  k_risk<<<RELS, 256, 0, stream>>>(logits_f, labels, pl, po, riskarr, flag);
  k_risk_sum<<<1, 128, 0, stream>>>(riskarr, d_out, flag);
}

// Round 3
// 995.476 us; speedup vs baseline: 1.5885x; 1.5885x over previous
//
#include <hip/hip_runtime.h>
#include <hip/hip_bf16.h>
#include <math.h>

typedef __hip_bfloat16 bf16;
typedef short s16x8 __attribute__((ext_vector_type(8)));
typedef float f32x16 __attribute__((ext_vector_type(16)));

// Problem constants (DocREModel)
constexpr int B = 4, H = 12, C = 1024, D = 768, E = 30, M = 8, P = 600;
constexpr int NL = 97, RELS = 96, EMB = 768;
constexpr int N = B * P;          // 2400 pairs
constexpr int KHEAD = 2 * D;      // 1536

static __device__ __forceinline__ float b2f(bf16 x) { return __bfloat162float(x); }

// fast f32 -> bf16 bits (round-half-up; inputs finite)
static __device__ __forceinline__ short f2bfbits(float f) {
  unsigned u = __builtin_bit_cast(unsigned, f);
  return (short)((u + 0x8000u) >> 16);
}

// dtype-agnostic load/store: BF=true -> buffer holds bf16, else float32
template <bool BF>
static __device__ __forceinline__ float ldf(const void* p, size_t i) {
  if (BF) return b2f(((const bf16*)p)[i]);
  return ((const float*)p)[i];
}
template <bool BF>
static __device__ __forceinline__ void stf(void* p, size_t i, float v) {
  if (BF) ((bf16*)p)[i] = __float2bfloat16(v);
  else    ((float*)p)[i] = v;
}

// ---------------------------------------------------------------------------
// Kernel 0: detect input dtype from mention_mask bit patterns.
// ---------------------------------------------------------------------------
__global__ __launch_bounds__(256) void k_detect(const unsigned int* __restrict__ mm,
                                                int* __restrict__ flag) {
  __shared__ int found;
  if (threadIdx.x == 0) found = 0;
  __syncthreads();
  for (int i = threadIdx.x; i < 480; i += 256) {
    unsigned int w = mm[i];
    if (w == 0x00003F80u || w == 0x3F803F80u) found = 1;
  }
  __syncthreads();
  if (threadIdx.x == 0) *flag = found;
}

// ---------------------------------------------------------------------------
// Kernel 1: ent_emb[b,e,d] = logsumexp over masked mentions of seq[b, idx, d]
// ---------------------------------------------------------------------------
struct EntEmbSmem { int sidx[M]; float smask[M]; };

template <bool BF>
static __device__ __forceinline__ void ent_emb_body(
    EntEmbSmem& s, const void* seq, const int* midx, const void* mmask,
    float* ent_emb) {
  int be = blockIdx.x;
  int b = be / E;
  if (threadIdx.x < M) {
    s.sidx[threadIdx.x] = midx[be * M + threadIdx.x] + 1;  // OFFSET
    s.smask[threadIdx.x] = ldf<BF>(mmask, be * M + threadIdx.x);
  }
  __syncthreads();
  for (int d = threadIdx.x; d < D; d += 256) {
    float v[M];
    float mx = -1e30f;
#pragma unroll
    for (int m = 0; m < M; m++) {
      v[m] = ldf<BF>(seq, ((size_t)(b * C + s.sidx[m])) * D + d);
      if (s.smask[m] != 0.0f) mx = fmaxf(mx, v[m]);
    }
    float sum = 0.f;
#pragma unroll
    for (int m = 0; m < M; m++)
      if (s.smask[m] != 0.0f) sum += expf(v[m] - mx);
    ent_emb[(size_t)be * D + d] = logf(sum) + mx;
  }
}

__global__ __launch_bounds__(256) void k_ent_emb(
    const void* seq, const int* midx, const void* mmask, float* ent_emb,
    const int* flag) {
  __shared__ EntEmbSmem s;
  if (*flag) ent_emb_body<true>(s, seq, midx, mmask, ent_emb);
  else       ent_emb_body<false>(s, seq, midx, mmask, ent_emb);
}

// ---------------------------------------------------------------------------
// Kernel 2: ent_att[b,e,h,c] = (sum_m mask*att[b,h,idx,c]) / cnt
// ---------------------------------------------------------------------------
struct EntAttSmem { int sidx[M]; float smask[M]; float sinv; };

template <bool BF>
static __device__ __forceinline__ void ent_att_body(
    EntAttSmem& s, const void* att, const int* midx, const void* mmask,
    float* ent_att) {
  int beh = blockIdx.x;
  int h = beh % H;
  int be = beh / H;
  int b = be / E;
  if (threadIdx.x < M) {
    s.sidx[threadIdx.x] = midx[be * M + threadIdx.x] + 1;
    s.smask[threadIdx.x] = ldf<BF>(mmask, be * M + threadIdx.x);
  }
  __syncthreads();
  if (threadIdx.x == 0) {
    float cnt = 0.f;
    for (int m = 0; m < M; m++) cnt += s.smask[m];
    s.sinv = 1.0f / cnt;
  }
  __syncthreads();
  for (int c = threadIdx.x; c < C; c += 256) {
    float sum = 0.f;
#pragma unroll
    for (int m = 0; m < M; m++)
      if (s.smask[m] != 0.0f)
        sum += ldf<BF>(att, (((size_t)b * H + h) * C + s.sidx[m]) * C + c);
    ent_att[((size_t)be * H + h) * C + c] = sum * s.sinv;
  }
}

__global__ __launch_bounds__(256) void k_ent_att(
    const void* att, const int* midx, const void* mmask, float* ent_att,
    const int* flag) {
  __shared__ EntAttSmem s;
  if (*flag) ent_att_body<true>(s, att, midx, mmask, ent_att);
  else       ent_att_body<false>(s, att, midx, mmask, ent_att);
}

// ---------------------------------------------------------------------------
// Kernel 3: ht_att[b,p,c] = normalize_c( mean_h( eA[h_i]*eA[t_i] ) )
// ---------------------------------------------------------------------------
__global__ __launch_bounds__(256) void k_ht_att(
    const float* __restrict__ ent_att, const int* __restrict__ hts,
    float* __restrict__ ht_att) {
  int bp = blockIdx.x;
  int b = bp / P;
  int hi = hts[bp * 2 + 0], ti = hts[bp * 2 + 1];
  const float* hA = ent_att + ((size_t)(b * E + hi)) * H * C;
  const float* tA = ent_att + ((size_t)(b * E + ti)) * H * C;
  float v[4];
  float loc = 0.f;
#pragma unroll
  for (int q = 0; q < 4; q++) {
    int c = threadIdx.x + q * 256;
    float s = 0.f;
#pragma unroll
    for (int h = 0; h < H; h++) s += hA[h * C + c] * tA[h * C + c];
    v[q] = s * (1.0f / H);
    loc += v[q];
  }
  __shared__ float red[256];
  red[threadIdx.x] = loc;
  __syncthreads();
  for (int off = 128; off > 0; off >>= 1) {
    if (threadIdx.x < off) red[threadIdx.x] += red[threadIdx.x + off];
    __syncthreads();
  }
  float inv = 1.0f / (red[0] + 1e-5f);
#pragma unroll
  for (int q = 0; q < 4; q++) {
    int c = threadIdx.x + q * 256;
    ht_att[(size_t)bp * C + c] = v[q] * inv;
  }
}

// ---------------------------------------------------------------------------
// Kernel 4: rs[b] = ht_att[b] (600x1024) @ seq[b] (1024x768)
// ---------------------------------------------------------------------------
struct GemmSmem { float At[64][33]; float Bt[32][64]; };

template <bool BF>
static __device__ __forceinline__ void rs_body(
    GemmSmem& s, const float* ht_att, const void* seq, float* rs) {
  int b = blockIdx.z;
  int r0 = blockIdx.x * 64;
  int c0 = blockIdx.y * 64;
  float acc[4][4] = {};
  int t = threadIdx.x;
  int ty = t / 16, tx = t % 16;
  for (int kt = 0; kt < C; kt += 32) {
#pragma unroll
    for (int l = 0; l < 8; l++) {
      int e = t + l * 256;
      int r = e / 32, kk = e % 32;
      int p = r0 + r;
      s.At[r][kk] = (p < P) ? ht_att[((size_t)b * P + p) * C + kt + kk] : 0.f;
    }
#pragma unroll
    for (int l = 0; l < 8; l++) {
      int e = t + l * 256;
      int kk = e / 64, cc = e % 64;
      s.Bt[kk][cc] = ldf<BF>(seq, ((size_t)b * C + kt + kk) * D + c0 + cc);
    }
    __syncthreads();
#pragma unroll
    for (int kk = 0; kk < 32; kk++) {
      float a0 = s.At[ty * 4 + 0][kk], a1 = s.At[ty * 4 + 1][kk];
      float a2 = s.At[ty * 4 + 2][kk], a3 = s.At[ty * 4 + 3][kk];
      float4 bv = *(const float4*)(&s.Bt[kk][tx * 4]);
      acc[0][0] += a0 * bv.x; acc[0][1] += a0 * bv.y; acc[0][2] += a0 * bv.z; acc[0][3] += a0 * bv.w;
      acc[1][0] += a1 * bv.x; acc[1][1] += a1 * bv.y; acc[1][2] += a1 * bv.z; acc[1][3] += a1 * bv.w;
      acc[2][0] += a2 * bv.x; acc[2][1] += a2 * bv.y; acc[2][2] += a2 * bv.z; acc[2][3] += a2 * bv.w;
      acc[3][0] += a3 * bv.x; acc[3][1] += a3 * bv.y; acc[3][2] += a3 * bv.z; acc[3][3] += a3 * bv.w;
    }
    __syncthreads();
  }
#pragma unroll
  for (int i = 0; i < 4; i++) {
    int p = r0 + ty * 4 + i;
    if (p < P) {
#pragma unroll
      for (int j = 0; j < 4; j++)
        rs[((size_t)b * P + p) * D + c0 + tx * 4 + j] = acc[i][j];
    }
  }
}

__global__ __launch_bounds__(256) void k_rs(
    const float* ht_att, const void* seq, float* rs, const int* flag) {
  __shared__ GemmSmem s;
  if (*flag) rs_body<true>(s, ht_att, seq, rs);
  else       rs_body<false>(s, ht_att, seq, rs);
}

// ---------------------------------------------------------------------------
// Kernel 5: hz/tz = tanh([hs|ts, rs] @ {head,tail}_W + bias)
// ---------------------------------------------------------------------------
struct HeadSmem { float At[64][33]; float Bt[32][64]; int ebase[64]; };

template <bool BF>
static __device__ __forceinline__ void head_body(
    HeadSmem& s, const float* ent_emb, const float* rs, const int* hts,
    const void* headW, const void* headb, const void* tailW, const void* tailb,
    float* hz, float* tz) {
  int which = blockIdx.z;
  const void* W = which ? tailW : headW;
  const void* bias = which ? tailb : headb;
  float* out = which ? tz : hz;
  int r0 = blockIdx.x * 64, c0 = blockIdx.y * 64;
  int t = threadIdx.x;
  if (t < 64) {
    int n = r0 + t;
    int nn = (n < N) ? n : 0;
    int b = nn / P, p = nn % P;
    int e = hts[(b * P + p) * 2 + which];
    s.ebase[t] = (b * E + e) * D;
  }
  __syncthreads();
  float acc[4][4] = {};
  int ty = t / 16, tx = t % 16;
  for (int kt = 0; kt < KHEAD; kt += 32) {
#pragma unroll
    for (int l = 0; l < 8; l++) {
      int e = t + l * 256;
      int r = e / 32, kk = e % 32;
      int n = r0 + r;
      int k = kt + kk;
      float v = 0.f;
      if (n < N) {
        if (k < D) v = ent_emb[s.ebase[r] + k];
        else       v = rs[(size_t)n * D + (k - D)];
      }
      s.At[r][kk] = v;
    }
#pragma unroll
    for (int l = 0; l < 8; l++) {
      int e = t + l * 256;
      int kk = e / 64, cc = e % 64;
      s.Bt[kk][cc] = ldf<BF>(W, (size_t)(kt + kk) * EMB + c0 + cc);
    }
    __syncthreads();
#pragma unroll
    for (int kk = 0; kk < 32; kk++) {
      float a0 = s.At[ty * 4 + 0][kk], a1 = s.At[ty * 4 + 1][kk];
      float a2 = s.At[ty * 4 + 2][kk], a3 = s.At[ty * 4 + 3][kk];
      float4 bv = *(const float4*)(&s.Bt[kk][tx * 4]);
      acc[0][0] += a0 * bv.x; acc[0][1] += a0 * bv.y; acc[0][2] += a0 * bv.z; acc[0][3] += a0 * bv.w;
      acc[1][0] += a1 * bv.x; acc[1][1] += a1 * bv.y; acc[1][2] += a1 * bv.z; acc[1][3] += a1 * bv.w;
      acc[2][0] += a2 * bv.x; acc[2][1] += a2 * bv.y; acc[2][2] += a2 * bv.z; acc[2][3] += a2 * bv.w;
      acc[3][0] += a3 * bv.x; acc[3][1] += a3 * bv.y; acc[3][2] += a3 * bv.z; acc[3][3] += a3 * bv.w;
    }
    __syncthreads();
  }
#pragma unroll
  for (int i = 0; i < 4; i++) {
    int n = r0 + ty * 4 + i;
    if (n < N) {
#pragma unroll
      for (int j = 0; j < 4; j++) {
        int cc = c0 + tx * 4 + j;
        out[(size_t)n * EMB + cc] = tanhf(acc[i][j] + ldf<BF>(bias, cc));
      }
    }
  }
}

__global__ __launch_bounds__(256) void k_head(
    const float* ent_emb, const float* rs, const int* hts,
    const void* headW, const void* headb, const void* tailW, const void* tailb,
    float* hz, float* tz, const int* flag) {
  __shared__ HeadSmem s;
  if (*flag) head_body<true>(s, ent_emb, rs, hts, headW, headb, tailW, tailb, hz, tz);
  else       head_body<false>(s, ent_emb, rs, hts, headW, headb, tailW, tailb, hz, tz);
}

// ---------------------------------------------------------------------------
// Kernel 6a: pre-pack bil_W into MFMA B-fragment order, bf16.
// Wt[(((kb*256 + s16)*4 + c)*64 + lane)*8 + t] =
//   W[kb*4096 + s16*16 + (lane>>5)*8 + t, c*32 + (lane&31)]  (0 if label>=97)
// grid (256, 12): s16 = blockIdx.x, kb = blockIdx.y. 256 threads.
// ---------------------------------------------------------------------------
struct TwSmem { float Ws[16][100]; };

template <bool BF>
static __device__ __forceinline__ void transpose_w_body(
    TwSmem& sm, const void* bilW, short* Wt) {
  int s16i = blockIdx.x, kb = blockIdx.y;
  int t = threadIdx.x;
  size_t kbase = (size_t)kb * 4096 + s16i * 16;
  for (int e = t; e < 16 * NL; e += 256) {
    int rr = e / NL, l = e % NL;
    sm.Ws[rr][l] = ldf<BF>(bilW, (kbase + rr) * NL + l);
  }
  __syncthreads();
  int c = t >> 6, lane = t & 63;
  int half = lane >> 5, col = lane & 31;
  int label = c * 32 + col;
  s16x8 v;
#pragma unroll
  for (int tt = 0; tt < 8; tt++) {
    float x = (label < NL) ? sm.Ws[half * 8 + tt][label] : 0.f;
    v[tt] = f2bfbits(x);
  }
  size_t off = ((((size_t)kb * 256 + s16i) * 4 + c) * 64 + lane) * 8;
  *(s16x8*)(Wt + off) = v;
}

__global__ __launch_bounds__(256) void k_transpose_w(
    const void* bilW, short* Wt, const int* flag) {
  __shared__ TwSmem sm;
  if (*flag) transpose_w_body<true>(sm, bilW, Wt);
  else       transpose_w_body<false>(sm, bilW, Wt);
}

// ---------------------------------------------------------------------------
// Kernel 6b: zero logits accumulator
// ---------------------------------------------------------------------------
__global__ __launch_bounds__(256) void k_zero_logits(float* __restrict__ logits_f) {
  int idx = blockIdx.x * 256 + threadIdx.x;
  if (idx < N * NL) logits_f[idx] = 0.f;
}

// ---------------------------------------------------------------------------
// Kernel 6c: bilinear logits via MFMA 32x32x16 bf16, A generated on the fly.
// A[n, i*64+j] = hz[n, kb*64+i] * tz[n, kb*64+j].
// grid (12 kb, 19 mb), 256 threads = 4 waves, each wave a 32-row strip.
// 4 label tiles of 32 (97 padded to 128). K-chunk 4096 -> 256 MFMA k-steps.
// No barriers in the K loop; partials combined via f32 atomicAdd.
// ---------------------------------------------------------------------------
__global__ __launch_bounds__(256) void k_logits_mfma(
    const float* __restrict__ hz, const float* __restrict__ tz,
    const short* __restrict__ Wt, float* __restrict__ logits_f) {
  int kb = blockIdx.x;
  int mb = blockIdx.y;
  int t = threadIdx.x;
  int w = t >> 6, lane = t & 63;
  int half = lane >> 5, r = lane & 31;
  int nb = mb * 128;

  __shared__ float hzs[128][65];
  {
    int row = t >> 1;
    int col0 = (t & 1) * 32;
    int n = nb + row;
#pragma unroll
    for (int q = 0; q < 8; q++) {
      float4 v = make_float4(0.f, 0.f, 0.f, 0.f);
      if (n < N) v = *(const float4*)(hz + (size_t)n * EMB + kb * 64 + col0 + q * 4);
      *(float4*)(&hzs[row][col0 + q * 4]) = v;
    }
  }
  // tz values this lane ever needs: j = q4*16 + half*8 + tt
  float tzr[4][8];
  {
    int n = nb + w * 32 + r;
#pragma unroll
    for (int q4 = 0; q4 < 4; q4++) {
      float4 a = make_float4(0.f, 0.f, 0.f, 0.f), b = a;
      if (n < N) {
        const float* p = tz + (size_t)n * EMB + kb * 64 + q4 * 16 + half * 8;
        a = *(const float4*)p;
        b = *(const float4*)(p + 4);
      }
      tzr[q4][0] = a.x; tzr[q4][1] = a.y; tzr[q4][2] = a.z; tzr[q4][3] = a.w;
      tzr[q4][4] = b.x; tzr[q4][5] = b.y; tzr[q4][6] = b.z; tzr[q4][7] = b.w;
    }
  }
  __syncthreads();

  f32x16 acc[4];
#pragma unroll
  for (int c = 0; c < 4; c++)
#pragma unroll
    for (int e = 0; e < 16; e++) acc[c][e] = 0.f;

  const int wrow = w * 32 + r;
  const short* wbase = Wt + (((size_t)kb * 256) * 4) * 64 * 8 + (size_t)lane * 8;

#pragma unroll 2
  for (int i = 0; i < 64; i++) {
    float hv = hzs[wrow][i];
#pragma unroll
    for (int q4 = 0; q4 < 4; q4++) {
      s16x8 af;
#pragma unroll
      for (int tt = 0; tt < 8; tt++) af[tt] = f2bfbits(hv * tzr[q4][tt]);
      int s16i = i * 4 + q4;
#pragma unroll
      for (int c = 0; c < 4; c++) {
        s16x8 bf = *(const s16x8*)(wbase + ((size_t)s16i * 4 + c) * 64 * 8);
        acc[c] = __builtin_amdgcn_mfma_f32_32x32x16_bf16(af, bf, acc[c], 0, 0, 0);
      }
    }
  }

  // C/D layout: col = lane&31 (label), row = (reg&3) + 8*(reg>>2) + 4*half
#pragma unroll
  for (int c = 0; c < 4; c++) {
    int label = c * 32 + r;
    if (label < NL) {
#pragma unroll
      for (int reg = 0; reg < 16; reg++) {
        int row = (reg & 3) + 8 * (reg >> 2) + 4 * half;
        int n = nb + w * 32 + row;
        if (n < N) atomicAdd(&logits_f[(size_t)n * NL + label], acc[c][reg]);
      }
    }
  }
}

// ---------------------------------------------------------------------------
// Kernel 6d: logits += bias; emit output logits in out dtype
// ---------------------------------------------------------------------------
template <bool BF>
static __device__ __forceinline__ void finish_body(
    float* logits_f, const void* bilb, void* out) {
  int idx = blockIdx.x * 256 + threadIdx.x;
  if (idx >= N * NL) return;
  int l = idx % NL;
  float s = logits_f[idx] + ldf<BF>(bilb, l);
  logits_f[idx] = s;
  stf<BF>(out, (size_t)idx + 1, s);  // out[0] = risk, out[1..] = logits
}

__global__ __launch_bounds__(256) void k_finish(
    float* logits_f, const void* bilb, void* out, const int* flag) {
  if (*flag) finish_body<true>(logits_f, bilb, out);
  else       finish_body<false>(logits_f, bilb, out);
}

// ---------------------------------------------------------------------------
// Kernel 7: per-relation PU risk. grid = RELS blocks.
// ---------------------------------------------------------------------------
struct RiskSmem { float red[5][256]; };

template <bool BF>
static __device__ __forceinline__ void risk_body(
    RiskSmem& sm, const float* logits_f, const int* labels,
    const void* priors_l, const void* priors_o, float* riskarr) {
  int r = blockIdx.x;  // 0..95
  int t = threadIdx.x;
  float s_neg = 0.f, s_pp = 0.f, s_pn = 0.f, c_neg = 0.f, c_pos = 0.f;
  for (int n = t; n < N; n += 256) {
    float sc = logits_f[(size_t)n * NL + (r + 1)] - logits_f[(size_t)n * NL];
    bool pos = labels[(size_t)n * NL + (r + 1)] == 1;
    float ln = 0.25f * (sc + 1.f) * (sc + 1.f);  // sign=-1
    float lp = 0.25f * (sc - 1.f) * (sc - 1.f);  // sign=+1
    if (pos) { c_pos += 1.f; s_pp += lp; s_pn += ln; }
    else     { c_neg += 1.f; s_neg += ln; }
  }
  sm.red[0][t] = s_neg; sm.red[1][t] = s_pp; sm.red[2][t] = s_pn;
  sm.red[3][t] = c_neg; sm.red[4][t] = c_pos;
  __syncthreads();
  for (int off = 128; off > 0; off >>= 1) {
    if (t < off) {
#pragma unroll
      for (int q = 0; q < 5; q++) sm.red[q][t] += sm.red[q][t + off];
    }
    __syncthreads();
  }
  if (t == 0) {
    float sq_neg   = sm.red[3][0] > 0.f ? sm.red[0][0] / fmaxf(sm.red[3][0], 1.f) : 0.f;
    float sq_pos_p = sm.red[4][0] > 0.f ? sm.red[1][0] / fmaxf(sm.red[4][0], 1.f) : 0.f;
    float sq_pos_n = sm.red[4][0] > 0.f ? sm.red[2][0] / fmaxf(sm.red[4][0], 1.f) : 0.f;
    float po = ldf<BF>(priors_o, r), pl = ldf<BF>(priors_l, r);
    float weight = sqrtf((1.f - po) / po);
    float pu = (po - pl) / (1.f - pl);
    float risk1 = (1.f - po) / (1.f - pu) * sq_neg - (pu - pu * po) / (1.f - pu) * sq_pos_n;
    float risk2 = po * sq_pos_p * weight;
    riskarr[r] = (risk1 < 0.f) ? -risk1 : (risk1 + risk2);  // BETA=0, GAMMA=1
  }
}

__global__ __launch_bounds__(256) void k_risk(
    const float* logits_f, const int* labels, const void* priors_l,
    const void* priors_o, float* riskarr, const int* flag) {
  __shared__ RiskSmem sm;
  if (*flag) risk_body<true>(sm, logits_f, labels, priors_l, priors_o, riskarr);
  else       risk_body<false>(sm, logits_f, labels, priors_l, priors_o, riskarr);
}

__global__ __launch_bounds__(128) void k_risk_sum(
    const float* __restrict__ riskarr, void* out, const int* flag) {
  __shared__ float red[128];
  int t = threadIdx.x;
  red[t] = (t < RELS) ? riskarr[t] : 0.f;
  __syncthreads();
  for (int off = 64; off > 0; off >>= 1) {
    if (t < off) red[t] += red[t + off];
    __syncthreads();
  }
  if (t == 0) {
    if (*flag) stf<true>(out, 0, red[0]);
    else       stf<false>(out, 0, red[0]);
  }
}

// ---------------------------------------------------------------------------
extern "C" void kernel_launch(void* const* d_in, const int* in_sizes, int n_in,
                              void* d_out, int out_size, void* d_ws, size_t ws_size,
                              hipStream_t stream) {
  const void* seq    = d_in[0];
  const void* att    = d_in[1];
  const int*  midx   = (const int*)d_in[2];
  const void* mmask  = d_in[3];
  const int*  hts    = (const int*)d_in[4];
  const int*  labels = (const int*)d_in[5];
  const void* pl     = d_in[6];
  const void* po     = d_in[7];
  const void* headW  = d_in[8];
  const void* headb  = d_in[9];
  const void* tailW  = d_in[10];
  const void* tailb  = d_in[11];
  const void* bilW   = d_in[12];
  const void* bilb   = d_in[13];

  // workspace layout: flag (64B), then floats.
  // Wt (12.6MB bf16) aliases ht_att+rs (17.2MB), both dead after k_head.
  int* flag = (int*)d_ws;
  float* w = (float*)d_ws + 16;
  float* ent_emb = w;                                   //  92160 f
  float* ent_att = w + (size_t)B * E * D;               // 1474560 f
  float* ht_att  = ent_att + (size_t)B * E * H * C;     // 2457600 f
  float* rs      = ht_att + (size_t)N * C;              // 1843200 f
  float* hz      = rs + (size_t)N * D;                  // 1843200 f
  float* tz      = hz + (size_t)N * EMB;                // 1843200 f
  float* logits_f = tz + (size_t)N * EMB;               // 232800 f
  float* riskarr  = logits_f + (size_t)N * NL;          // 96 f
  short* Wt      = (short*)ht_att;                      // 6291456 bf16 (alias)

  k_detect<<<1, 256, 0, stream>>>((const unsigned int*)mmask, flag);
  k_ent_emb<<<B * E, 256, 0, stream>>>(seq, midx, mmask, ent_emb, flag);
  k_ent_att<<<B * E * H, 256, 0, stream>>>(att, midx, mmask, ent_att, flag);
  k_ht_att<<<B * P, 256, 0, stream>>>(ent_att, hts, ht_att);
  k_rs<<<dim3((P + 63) / 64, D / 64, B), 256, 0, stream>>>(ht_att, seq, rs, flag);
  k_head<<<dim3((N + 63) / 64, EMB / 64, 2), 256, 0, stream>>>(
      ent_emb, rs, hts, headW, headb, tailW, tailb, hz, tz, flag);
  k_transpose_w<<<dim3(256, 12), 256, 0, stream>>>(bilW, Wt, flag);
  k_zero_logits<<<(N * NL + 255) / 256, 256, 0, stream>>>(logits_f);
  k_logits_mfma<<<dim3(12, (N + 127) / 128), 256, 0, stream>>>(hz, tz, Wt, logits_f);
  k_finish<<<(N * NL + 255) / 256, 256, 0, stream>>>(logits_f, bilb, d_out, flag);
  k_risk<<<RELS, 256, 0, stream>>>(logits_f, labels, pl, po, riskarr, flag);
  k_risk_sum<<<1, 128, 0, stream>>>(riskarr, d_out, flag);
}

// Round 4
// 650.987 us; speedup vs baseline: 2.4290x; 1.5292x over previous
//
#include <hip/hip_runtime.h>
#include <hip/hip_bf16.h>
#include <math.h>

typedef __hip_bfloat16 bf16;
typedef short s16x8 __attribute__((ext_vector_type(8)));
typedef float f32x16 __attribute__((ext_vector_type(16)));

// Problem constants (DocREModel)
constexpr int B = 4, H = 12, C = 1024, D = 768, E = 30, M = 8, P = 600;
constexpr int NL = 97, RELS = 96, EMB = 768;
constexpr int N = B * P;          // 2400 pairs
constexpr int KHEAD = 2 * D;      // 1536
constexpr int MG = 76;            // 2432/32 row groups (N padded to 2432)

static __device__ __forceinline__ float b2f(bf16 x) { return __bfloat162float(x); }

// fast f32 -> bf16 bits (round-half-up; inputs finite)
static __device__ __forceinline__ short f2bfbits(float f) {
  unsigned u = __builtin_bit_cast(unsigned, f);
  return (short)((u + 0x8000u) >> 16);
}

// dtype-agnostic load/store: BF=true -> buffer holds bf16, else float32
template <bool BF>
static __device__ __forceinline__ float ldf(const void* p, size_t i) {
  if (BF) return b2f(((const bf16*)p)[i]);
  return ((const float*)p)[i];
}
template <bool BF>
static __device__ __forceinline__ void stf(void* p, size_t i, float v) {
  if (BF) ((bf16*)p)[i] = __float2bfloat16(v);
  else    ((float*)p)[i] = v;
}

// ---------------------------------------------------------------------------
// Kernel 0: detect input dtype from mention_mask bit patterns.
// ---------------------------------------------------------------------------
__global__ __launch_bounds__(256) void k_detect(const unsigned int* __restrict__ mm,
                                                int* __restrict__ flag) {
  __shared__ int found;
  if (threadIdx.x == 0) found = 0;
  __syncthreads();
  for (int i = threadIdx.x; i < 480; i += 256) {
    unsigned int w = mm[i];
    if (w == 0x00003F80u || w == 0x3F803F80u) found = 1;
  }
  __syncthreads();
  if (threadIdx.x == 0) *flag = found;
}

// ---------------------------------------------------------------------------
// Kernel 1: ent_emb[b,e,d] = logsumexp over masked mentions of seq[b, idx, d]
// ---------------------------------------------------------------------------
struct EntEmbSmem { int sidx[M]; float smask[M]; };

template <bool BF>
static __device__ __forceinline__ void ent_emb_body(
    EntEmbSmem& s, const void* seq, const int* midx, const void* mmask,
    float* ent_emb) {
  int be = blockIdx.x;
  int b = be / E;
  if (threadIdx.x < M) {
    s.sidx[threadIdx.x] = midx[be * M + threadIdx.x] + 1;  // OFFSET
    s.smask[threadIdx.x] = ldf<BF>(mmask, be * M + threadIdx.x);
  }
  __syncthreads();
  for (int d = threadIdx.x; d < D; d += 256) {
    float v[M];
    float mx = -1e30f;
#pragma unroll
    for (int m = 0; m < M; m++) {
      v[m] = ldf<BF>(seq, ((size_t)(b * C + s.sidx[m])) * D + d);
      if (s.smask[m] != 0.0f) mx = fmaxf(mx, v[m]);
    }
    float sum = 0.f;
#pragma unroll
    for (int m = 0; m < M; m++)
      if (s.smask[m] != 0.0f) sum += expf(v[m] - mx);
    ent_emb[(size_t)be * D + d] = logf(sum) + mx;
  }
}

__global__ __launch_bounds__(256) void k_ent_emb(
    const void* seq, const int* midx, const void* mmask, float* ent_emb,
    const int* flag) {
  __shared__ EntEmbSmem s;
  if (*flag) ent_emb_body<true>(s, seq, midx, mmask, ent_emb);
  else       ent_emb_body<false>(s, seq, midx, mmask, ent_emb);
}

// ---------------------------------------------------------------------------
// Kernel 2: ent_att[b,e,h,c] = (sum_m mask*att[b,h,idx,c]) / cnt
// ---------------------------------------------------------------------------
struct EntAttSmem { int sidx[M]; float smask[M]; float sinv; };

template <bool BF>
static __device__ __forceinline__ void ent_att_body(
    EntAttSmem& s, const void* att, const int* midx, const void* mmask,
    float* ent_att) {
  int beh = blockIdx.x;
  int h = beh % H;
  int be = beh / H;
  int b = be / E;
  if (threadIdx.x < M) {
    s.sidx[threadIdx.x] = midx[be * M + threadIdx.x] + 1;
    s.smask[threadIdx.x] = ldf<BF>(mmask, be * M + threadIdx.x);
  }
  __syncthreads();
  if (threadIdx.x == 0) {
    float cnt = 0.f;
    for (int m = 0; m < M; m++) cnt += s.smask[m];
    s.sinv = 1.0f / cnt;
  }
  __syncthreads();
  for (int c = threadIdx.x; c < C; c += 256) {
    float sum = 0.f;
#pragma unroll
    for (int m = 0; m < M; m++)
      if (s.smask[m] != 0.0f)
        sum += ldf<BF>(att, (((size_t)b * H + h) * C + s.sidx[m]) * C + c);
    ent_att[((size_t)be * H + h) * C + c] = sum * s.sinv;
  }
}

__global__ __launch_bounds__(256) void k_ent_att(
    const void* att, const int* midx, const void* mmask, float* ent_att,
    const int* flag) {
  __shared__ EntAttSmem s;
  if (*flag) ent_att_body<true>(s, att, midx, mmask, ent_att);
  else       ent_att_body<false>(s, att, midx, mmask, ent_att);
}

// ---------------------------------------------------------------------------
// Kernel 3: ht_att[b,p,c] = normalize_c( mean_h( eA[h_i]*eA[t_i] ) )
// ---------------------------------------------------------------------------
__global__ __launch_bounds__(256) void k_ht_att(
    const float* __restrict__ ent_att, const int* __restrict__ hts,
    float* __restrict__ ht_att) {
  int bp = blockIdx.x;
  int b = bp / P;
  int hi = hts[bp * 2 + 0], ti = hts[bp * 2 + 1];
  const float* hA = ent_att + ((size_t)(b * E + hi)) * H * C;
  const float* tA = ent_att + ((size_t)(b * E + ti)) * H * C;
  float v[4];
  float loc = 0.f;
#pragma unroll
  for (int q = 0; q < 4; q++) {
    int c = threadIdx.x + q * 256;
    float s = 0.f;
#pragma unroll
    for (int h = 0; h < H; h++) s += hA[h * C + c] * tA[h * C + c];
    v[q] = s * (1.0f / H);
    loc += v[q];
  }
  __shared__ float red[256];
  red[threadIdx.x] = loc;
  __syncthreads();
  for (int off = 128; off > 0; off >>= 1) {
    if (threadIdx.x < off) red[threadIdx.x] += red[threadIdx.x + off];
    __syncthreads();
  }
  float inv = 1.0f / (red[0] + 1e-5f);
#pragma unroll
  for (int q = 0; q < 4; q++) {
    int c = threadIdx.x + q * 256;
    ht_att[(size_t)bp * C + c] = v[q] * inv;
  }
}

// ---------------------------------------------------------------------------
// Kernel 4: rs[b] = ht_att[b] (600x1024) @ seq[b] (1024x768)
// Output written DIRECTLY as bf16 MFMA A-fragments (Afrag_rs), since rs is
// only ever consumed as the k>=768 half of the head/tail A matrices.
// Afrag_rs[((mg*48 + kc)*64 + half*32 + rr)*8 + tt] = rs[n=mg*32+rr][c],
//   where c = kc*16 + half*8 + tt.
// ---------------------------------------------------------------------------
struct GemmSmem { float At[64][33]; float Bt[32][64]; };

template <bool BF>
static __device__ __forceinline__ void rs_body(
    GemmSmem& s, const float* ht_att, const void* seq, short* Ars) {
  int b = blockIdx.z;
  int r0 = blockIdx.x * 64;
  int c0 = blockIdx.y * 64;
  float acc[4][4] = {};
  int t = threadIdx.x;
  int ty = t / 16, tx = t % 16;
  for (int kt = 0; kt < C; kt += 32) {
#pragma unroll
    for (int l = 0; l < 8; l++) {
      int e = t + l * 256;
      int r = e / 32, kk = e % 32;
      int p = r0 + r;
      s.At[r][kk] = (p < P) ? ht_att[((size_t)b * P + p) * C + kt + kk] : 0.f;
    }
#pragma unroll
    for (int l = 0; l < 8; l++) {
      int e = t + l * 256;
      int kk = e / 64, cc = e % 64;
      s.Bt[kk][cc] = ldf<BF>(seq, ((size_t)b * C + kt + kk) * D + c0 + cc);
    }
    __syncthreads();
#pragma unroll
    for (int kk = 0; kk < 32; kk++) {
      float a0 = s.At[ty * 4 + 0][kk], a1 = s.At[ty * 4 + 1][kk];
      float a2 = s.At[ty * 4 + 2][kk], a3 = s.At[ty * 4 + 3][kk];
      float4 bv = *(const float4*)(&s.Bt[kk][tx * 4]);
      acc[0][0] += a0 * bv.x; acc[0][1] += a0 * bv.y; acc[0][2] += a0 * bv.z; acc[0][3] += a0 * bv.w;
      acc[1][0] += a1 * bv.x; acc[1][1] += a1 * bv.y; acc[1][2] += a1 * bv.z; acc[1][3] += a1 * bv.w;
      acc[2][0] += a2 * bv.x; acc[2][1] += a2 * bv.y; acc[2][2] += a2 * bv.z; acc[2][3] += a2 * bv.w;
      acc[3][0] += a3 * bv.x; acc[3][1] += a3 * bv.y; acc[3][2] += a3 * bv.z; acc[3][3] += a3 * bv.w;
    }
    __syncthreads();
  }
#pragma unroll
  for (int i = 0; i < 4; i++) {
    int p = r0 + ty * 4 + i;
    if (p < P) {
      int n = b * P + p;
      int mg = n >> 5, rr = n & 31;
#pragma unroll
      for (int j = 0; j < 4; j++) {
        int c = c0 + tx * 4 + j;
        int kc = c >> 4, half = (c >> 3) & 1, tt = c & 7;
        Ars[(((size_t)mg * 48 + kc) * 64 + half * 32 + rr) * 8 + tt] =
            f2bfbits(acc[i][j]);
      }
    }
  }
}

__global__ __launch_bounds__(256) void k_rs(
    const float* ht_att, const void* seq, short* Ars, const int* flag) {
  __shared__ GemmSmem s;
  if (*flag) rs_body<true>(s, ht_att, seq, Ars);
  else       rs_body<false>(s, ht_att, seq, Ars);
}

// ---------------------------------------------------------------------------
// Kernel 5a: build hs/ts halves of the head/tail A matrices in fragment order.
// Afrag[(mg*48 + kc)*64*8 + lane*8 + tt] = ent_emb[ebase(row,which) + k]
//   row = mg*32 + (lane&31), k = kc*16 + (lane>>5)*8 + tt.
// Also zeroes the pad rows (mg=75) of Afrag_rs.
// grid (76, 2), 256 threads.
// ---------------------------------------------------------------------------
__global__ __launch_bounds__(256) void k_prep_ahs(
    const float* __restrict__ ent_emb, const int* __restrict__ hts,
    short* __restrict__ Ahs, short* __restrict__ Ats, short* __restrict__ Ars) {
  int mg = blockIdx.x, which = blockIdx.y;
  short* Adst = which ? Ats : Ahs;
  int t = threadIdx.x, lane = t & 63, kc0 = t >> 6;
  int rr = lane & 31, half = lane >> 5;
  int row = mg * 32 + rr;
  bool valid = row < N;
  size_t base = 0;
  if (valid) {
    int b = row / P, p = row % P;
    int e = hts[(b * P + p) * 2 + which];
    base = (size_t)(b * E + e) * D;
  }
#pragma unroll
  for (int q = 0; q < 12; q++) {
    int kc = kc0 + q * 4;
    s16x8 v = {0, 0, 0, 0, 0, 0, 0, 0};
    if (valid) {
      const float* p = ent_emb + base + kc * 16 + half * 8;
      float4 v0 = *(const float4*)p;
      float4 v1 = *(const float4*)(p + 4);
      v[0] = f2bfbits(v0.x); v[1] = f2bfbits(v0.y);
      v[2] = f2bfbits(v0.z); v[3] = f2bfbits(v0.w);
      v[4] = f2bfbits(v1.x); v[5] = f2bfbits(v1.y);
      v[6] = f2bfbits(v1.z); v[7] = f2bfbits(v1.w);
    }
    *(s16x8*)(Adst + (((size_t)mg * 48 + kc) * 64 + lane) * 8) = v;
    if (which == 0 && mg == MG - 1) {
      s16x8 z = {0, 0, 0, 0, 0, 0, 0, 0};
      *(s16x8*)(Ars + (((size_t)(MG - 1) * 48 + kc) * 64 + lane) * 8) = z;
    }
  }
}

// ---------------------------------------------------------------------------
// Kernel 5b: pack head_W / tail_W into B-fragment order (bf16) + biases f32.
// Wf[((kc*24 + cg)*64 + lane)*8 + tt] = W[kc*16 + (lane>>5)*8 + tt][cg*32 + (lane&31)]
// grid (96, 2), 256 threads.
// ---------------------------------------------------------------------------
struct PrepWSmem { short Ws[16][776]; };

template <bool BF>
static __device__ __forceinline__ void prep_w_body(
    PrepWSmem& sm, const void* headW, const void* headb,
    const void* tailW, const void* tailb,
    short* Wfh, short* Wft, float* bias_h, float* bias_t) {
  int kc = blockIdx.x, which = blockIdx.y;
  const void* W = which ? tailW : headW;
  short* Wf = which ? Wft : Wfh;
  int t = threadIdx.x;
  for (int e = t; e < 16 * EMB; e += 256) {
    int kk = e / EMB, c = e % EMB;
    sm.Ws[kk][c] = f2bfbits(ldf<BF>(W, (size_t)(kc * 16 + kk) * EMB + c));
  }
  __syncthreads();
  int lane = t & 63, cg0 = t >> 6;
  int rr = lane & 31, half = lane >> 5;
#pragma unroll
  for (int q = 0; q < 6; q++) {
    int cg = cg0 + q * 4;
    int col = cg * 32 + rr;
    s16x8 v;
#pragma unroll
    for (int tt = 0; tt < 8; tt++) v[tt] = sm.Ws[half * 8 + tt][col];
    *(s16x8*)(Wf + (((size_t)kc * 24 + cg) * 64 + lane) * 8) = v;
  }
  if (kc == 0) {
    const void* bsrc = which ? tailb : headb;
    float* bdst = which ? bias_t : bias_h;
    for (int c = t; c < EMB; c += 256) bdst[c] = ldf<BF>(bsrc, c);
  }
}

__global__ __launch_bounds__(256) void k_prep_w(
    const void* headW, const void* headb, const void* tailW, const void* tailb,
    short* Wfh, short* Wft, float* bias_h, float* bias_t, const int* flag) {
  __shared__ PrepWSmem sm;
  if (*flag) prep_w_body<true>(sm, headW, headb, tailW, tailb, Wfh, Wft, bias_h, bias_t);
  else       prep_w_body<false>(sm, headW, headb, tailW, tailb, Wfh, Wft, bias_h, bias_t);
}

// ---------------------------------------------------------------------------
// Kernel 5c: hz/tz = tanh(A @ W + bias) via MFMA 32x32x16 bf16.
// All operands pre-packed in fragment order: zero LDS, zero barriers.
// grid (19 mtiles, 6 ntiles, 2 which), 256 threads = 4 waves (2x2 per block),
// each wave a 64x64 tile = 2x2 MFMA accumulators, K = 1536 = 96 chunks.
// ---------------------------------------------------------------------------
__global__ __launch_bounds__(256) void k_head_mfma(
    const short* __restrict__ Ahs, const short* __restrict__ Ats,
    const short* __restrict__ Ars,
    const short* __restrict__ Wfh, const short* __restrict__ Wft,
    const float* __restrict__ bias_h, const float* __restrict__ bias_t,
    float* __restrict__ hz, float* __restrict__ tz) {
  int mt = blockIdx.x, nt = blockIdx.y, which = blockIdx.z;
  const short* Ahead = which ? Ats : Ahs;
  const short* Wf = which ? Wft : Wfh;
  const float* bias = which ? bias_t : bias_h;
  float* out = which ? tz : hz;

  int t = threadIdx.x, w = t >> 6, lane = t & 63;
  int half = lane >> 5, r = lane & 31;
  int wm = w >> 1, wn = w & 1;
  int mg0 = mt * 4 + wm * 2;
  int cg0 = nt * 4 + wn * 2;

  f32x16 acc[2][2];
#pragma unroll
  for (int i = 0; i < 2; i++)
#pragma unroll
    for (int j = 0; j < 2; j++)
#pragma unroll
      for (int e = 0; e < 16; e++) acc[i][j][e] = 0.f;

  // K chunks 0..47: hs/ts half (which-specific A)
#pragma unroll 4
  for (int kc = 0; kc < 48; kc++) {
    s16x8 a0 = *(const s16x8*)(Ahead + (((size_t)(mg0 + 0) * 48 + kc) * 64 + lane) * 8);
    s16x8 a1 = *(const s16x8*)(Ahead + (((size_t)(mg0 + 1) * 48 + kc) * 64 + lane) * 8);
    s16x8 b0 = *(const s16x8*)(Wf + (((size_t)kc * 24 + cg0 + 0) * 64 + lane) * 8);
    s16x8 b1 = *(const s16x8*)(Wf + (((size_t)kc * 24 + cg0 + 1) * 64 + lane) * 8);
    acc[0][0] = __builtin_amdgcn_mfma_f32_32x32x16_bf16(a0, b0, acc[0][0], 0, 0, 0);
    acc[0][1] = __builtin_amdgcn_mfma_f32_32x32x16_bf16(a0, b1, acc[0][1], 0, 0, 0);
    acc[1][0] = __builtin_amdgcn_mfma_f32_32x32x16_bf16(a1, b0, acc[1][0], 0, 0, 0);
    acc[1][1] = __builtin_amdgcn_mfma_f32_32x32x16_bf16(a1, b1, acc[1][1], 0, 0, 0);
  }
  // K chunks 48..95: rs half (shared A)
#pragma unroll 4
  for (int kc = 0; kc < 48; kc++) {
    s16x8 a0 = *(const s16x8*)(Ars + (((size_t)(mg0 + 0) * 48 + kc) * 64 + lane) * 8);
    s16x8 a1 = *(const s16x8*)(Ars + (((size_t)(mg0 + 1) * 48 + kc) * 64 + lane) * 8);
    s16x8 b0 = *(const s16x8*)(Wf + (((size_t)(kc + 48) * 24 + cg0 + 0) * 64 + lane) * 8);
    s16x8 b1 = *(const s16x8*)(Wf + (((size_t)(kc + 48) * 24 + cg0 + 1) * 64 + lane) * 8);
    acc[0][0] = __builtin_amdgcn_mfma_f32_32x32x16_bf16(a0, b0, acc[0][0], 0, 0, 0);
    acc[0][1] = __builtin_amdgcn_mfma_f32_32x32x16_bf16(a0, b1, acc[0][1], 0, 0, 0);
    acc[1][0] = __builtin_amdgcn_mfma_f32_32x32x16_bf16(a1, b0, acc[1][0], 0, 0, 0);
    acc[1][1] = __builtin_amdgcn_mfma_f32_32x32x16_bf16(a1, b1, acc[1][1], 0, 0, 0);
  }

  // C/D layout: col = lane&31, row = (reg&3) + 8*(reg>>2) + 4*half
#pragma unroll
  for (int i = 0; i < 2; i++) {
    int rowbase = (mg0 + i) * 32 + 4 * half;
#pragma unroll
    for (int j = 0; j < 2; j++) {
      int col = (cg0 + j) * 32 + r;
      float bv = bias[col];
#pragma unroll
      for (int reg = 0; reg < 16; reg++) {
        int n = rowbase + (reg & 3) + 8 * (reg >> 2);
        if (n < N) out[(size_t)n * EMB + col] = tanhf(acc[i][j][reg] + bv);
      }
    }
  }
}

// ---------------------------------------------------------------------------
// Kernel 6a: pre-pack bil_W into MFMA B-fragment order, bf16.
// ---------------------------------------------------------------------------
struct TwSmem { float Ws[16][100]; };

template <bool BF>
static __device__ __forceinline__ void transpose_w_body(
    TwSmem& sm, const void* bilW, short* Wt) {
  int s16i = blockIdx.x, kb = blockIdx.y;
  int t = threadIdx.x;
  size_t kbase = (size_t)kb * 4096 + s16i * 16;
  for (int e = t; e < 16 * NL; e += 256) {
    int rr = e / NL, l = e % NL;
    sm.Ws[rr][l] = ldf<BF>(bilW, (kbase + rr) * NL + l);
  }
  __syncthreads();
  int c = t >> 6, lane = t & 63;
  int half = lane >> 5, col = lane & 31;
  int label = c * 32 + col;
  s16x8 v;
#pragma unroll
  for (int tt = 0; tt < 8; tt++) {
    float x = (label < NL) ? sm.Ws[half * 8 + tt][label] : 0.f;
    v[tt] = f2bfbits(x);
  }
  size_t off = ((((size_t)kb * 256 + s16i) * 4 + c) * 64 + lane) * 8;
  *(s16x8*)(Wt + off) = v;
}

__global__ __launch_bounds__(256) void k_transpose_w(
    const void* bilW, short* Wt, const int* flag) {
  __shared__ TwSmem sm;
  if (*flag) transpose_w_body<true>(sm, bilW, Wt);
  else       transpose_w_body<false>(sm, bilW, Wt);
}

// ---------------------------------------------------------------------------
// Kernel 6b: zero logits accumulator
// ---------------------------------------------------------------------------
__global__ __launch_bounds__(256) void k_zero_logits(float* __restrict__ logits_f) {
  int idx = blockIdx.x * 256 + threadIdx.x;
  if (idx < N * NL) logits_f[idx] = 0.f;
}

// ---------------------------------------------------------------------------
// Kernel 6c: bilinear logits via MFMA 32x32x16 bf16, A generated on the fly.
// ---------------------------------------------------------------------------
__global__ __launch_bounds__(256) void k_logits_mfma(
    const float* __restrict__ hz, const float* __restrict__ tz,
    const short* __restrict__ Wt, float* __restrict__ logits_f) {
  int kb = blockIdx.x;
  int mb = blockIdx.y;
  int t = threadIdx.x;
  int w = t >> 6, lane = t & 63;
  int half = lane >> 5, r = lane & 31;
  int nb = mb * 128;

  __shared__ float hzs[128][65];
  {
    int row = t >> 1;
    int col0 = (t & 1) * 32;
    int n = nb + row;
#pragma unroll
    for (int q = 0; q < 8; q++) {
      float4 v = make_float4(0.f, 0.f, 0.f, 0.f);
      if (n < N) v = *(const float4*)(hz + (size_t)n * EMB + kb * 64 + col0 + q * 4);
      *(float4*)(&hzs[row][col0 + q * 4]) = v;
    }
  }
  float tzr[4][8];
  {
    int n = nb + w * 32 + r;
#pragma unroll
    for (int q4 = 0; q4 < 4; q4++) {
      float4 a = make_float4(0.f, 0.f, 0.f, 0.f), b = a;
      if (n < N) {
        const float* p = tz + (size_t)n * EMB + kb * 64 + q4 * 16 + half * 8;
        a = *(const float4*)p;
        b = *(const float4*)(p + 4);
      }
      tzr[q4][0] = a.x; tzr[q4][1] = a.y; tzr[q4][2] = a.z; tzr[q4][3] = a.w;
      tzr[q4][4] = b.x; tzr[q4][5] = b.y; tzr[q4][6] = b.z; tzr[q4][7] = b.w;
    }
  }
  __syncthreads();

  f32x16 acc[4];
#pragma unroll
  for (int c = 0; c < 4; c++)
#pragma unroll
    for (int e = 0; e < 16; e++) acc[c][e] = 0.f;

  const int wrow = w * 32 + r;
  const short* wbase = Wt + (((size_t)kb * 256) * 4) * 64 * 8 + (size_t)lane * 8;

#pragma unroll 2
  for (int i = 0; i < 64; i++) {
    float hv = hzs[wrow][i];
#pragma unroll
    for (int q4 = 0; q4 < 4; q4++) {
      s16x8 af;
#pragma unroll
      for (int tt = 0; tt < 8; tt++) af[tt] = f2bfbits(hv * tzr[q4][tt]);
      int s16i = i * 4 + q4;
#pragma unroll
      for (int c = 0; c < 4; c++) {
        s16x8 bf = *(const s16x8*)(wbase + ((size_t)s16i * 4 + c) * 64 * 8);
        acc[c] = __builtin_amdgcn_mfma_f32_32x32x16_bf16(af, bf, acc[c], 0, 0, 0);
      }
    }
  }

#pragma unroll
  for (int c = 0; c < 4; c++) {
    int label = c * 32 + r;
    if (label < NL) {
#pragma unroll
      for (int reg = 0; reg < 16; reg++) {
        int row = (reg & 3) + 8 * (reg >> 2) + 4 * half;
        int n = nb + w * 32 + row;
        if (n < N) atomicAdd(&logits_f[(size_t)n * NL + label], acc[c][reg]);
      }
    }
  }
}

// ---------------------------------------------------------------------------
// Kernel 6d: logits += bias; emit output logits in out dtype
// ---------------------------------------------------------------------------
template <bool BF>
static __device__ __forceinline__ void finish_body(
    float* logits_f, const void* bilb, void* out) {
  int idx = blockIdx.x * 256 + threadIdx.x;
  if (idx >= N * NL) return;
  int l = idx % NL;
  float s = logits_f[idx] + ldf<BF>(bilb, l);
  logits_f[idx] = s;
  stf<BF>(out, (size_t)idx + 1, s);  // out[0] = risk, out[1..] = logits
}

__global__ __launch_bounds__(256) void k_finish(
    float* logits_f, const void* bilb, void* out, const int* flag) {
  if (*flag) finish_body<true>(logits_f, bilb, out);
  else       finish_body<false>(logits_f, bilb, out);
}

// ---------------------------------------------------------------------------
// Kernel 7: per-relation PU risk. grid = RELS blocks.
// ---------------------------------------------------------------------------
struct RiskSmem { float red[5][256]; };

template <bool BF>
static __device__ __forceinline__ void risk_body(
    RiskSmem& sm, const float* logits_f, const int* labels,
    const void* priors_l, const void* priors_o, float* riskarr) {
  int r = blockIdx.x;  // 0..95
  int t = threadIdx.x;
  float s_neg = 0.f, s_pp = 0.f, s_pn = 0.f, c_neg = 0.f, c_pos = 0.f;
  for (int n = t; n < N; n += 256) {
    float sc = logits_f[(size_t)n * NL + (r + 1)] - logits_f[(size_t)n * NL];
    bool pos = labels[(size_t)n * NL + (r + 1)] == 1;
    float ln = 0.25f * (sc + 1.f) * (sc + 1.f);  // sign=-1
    float lp = 0.25f * (sc - 1.f) * (sc - 1.f);  // sign=+1
    if (pos) { c_pos += 1.f; s_pp += lp; s_pn += ln; }
    else     { c_neg += 1.f; s_neg += ln; }
  }
  sm.red[0][t] = s_neg; sm.red[1][t] = s_pp; sm.red[2][t] = s_pn;
  sm.red[3][t] = c_neg; sm.red[4][t] = c_pos;
  __syncthreads();
  for (int off = 128; off > 0; off >>= 1) {
    if (t < off) {
#pragma unroll
      for (int q = 0; q < 5; q++) sm.red[q][t] += sm.red[q][t + off];
    }
    __syncthreads();
  }
  if (t == 0) {
    float sq_neg   = sm.red[3][0] > 0.f ? sm.red[0][0] / fmaxf(sm.red[3][0], 1.f) : 0.f;
    float sq_pos_p = sm.red[4][0] > 0.f ? sm.red[1][0] / fmaxf(sm.red[4][0], 1.f) : 0.f;
    float sq_pos_n = sm.red[4][0] > 0.f ? sm.red[2][0] / fmaxf(sm.red[4][0], 1.f) : 0.f;
    float po = ldf<BF>(priors_o, r), pl = ldf<BF>(priors_l, r);
    float weight = sqrtf((1.f - po) / po);
    float pu = (po - pl) / (1.f - pl);
    float risk1 = (1.f - po) / (1.f - pu) * sq_neg - (pu - pu * po) / (1.f - pu) * sq_pos_n;
    float risk2 = po * sq_pos_p * weight;
    riskarr[r] = (risk1 < 0.f) ? -risk1 : (risk1 + risk2);  // BETA=0, GAMMA=1
  }
}

__global__ __launch_bounds__(256) void k_risk(
    const float* logits_f, const int* labels, const void* priors_l,
    const void* priors_o, float* riskarr, const int* flag) {
  __shared__ RiskSmem sm;
  if (*flag) risk_body<true>(sm, logits_f, labels, priors_l, priors_o, riskarr);
  else       risk_body<false>(sm, logits_f, labels, priors_l, priors_o, riskarr);
}

__global__ __launch_bounds__(128) void k_risk_sum(
    const float* __restrict__ riskarr, void* out, const int* flag) {
  __shared__ float red[128];
  int t = threadIdx.x;
  red[t] = (t < RELS) ? riskarr[t] : 0.f;
  __syncthreads();
  for (int off = 64; off > 0; off >>= 1) {
    if (t < off) red[t] += red[t + off];
    __syncthreads();
  }
  if (t == 0) {
    if (*flag) stf<true>(out, 0, red[0]);
    else       stf<false>(out, 0, red[0]);
  }
}

// ---------------------------------------------------------------------------
extern "C" void kernel_launch(void* const* d_in, const int* in_sizes, int n_in,
                              void* d_out, int out_size, void* d_ws, size_t ws_size,
                              hipStream_t stream) {
  const void* seq    = d_in[0];
  const void* att    = d_in[1];
  const int*  midx   = (const int*)d_in[2];
  const void* mmask  = d_in[3];
  const int*  hts    = (const int*)d_in[4];
  const int*  labels = (const int*)d_in[5];
  const void* pl     = d_in[6];
  const void* po     = d_in[7];
  const void* headW  = d_in[8];
  const void* headb  = d_in[9];
  const void* tailW  = d_in[10];
  const void* tailb  = d_in[11];
  const void* bilW   = d_in[12];
  const void* bilb   = d_in[13];

  // workspace layout (floats after 64B flag). Lifetime aliasing:
  //  slot1 (1474560 f): ent_att -> Afrag_rs -> (with slot2) Wt_bil
  //  slot2 (2457600 f): ht_att  -> Afrag_hs + Afrag_ts -> Wt_bil tail
  //  slot3 (1179648 f): Wfrag_head + Wfrag_tail
  // Peak ~36.5 MB (< proven 39.1 MB round-3 footprint).
  int* flag = (int*)d_ws;
  float* w = (float*)d_ws + 16;
  float* ent_emb  = w;                                   //   92160 f
  float* hz       = ent_emb + (size_t)B * E * D;         // 1843200 f
  float* tz       = hz + (size_t)N * EMB;                // 1843200 f
  float* logits_f = tz + (size_t)N * EMB;                //  232800 f
  float* riskarr  = logits_f + (size_t)N * NL;           //      96 f
  float* bias_h   = riskarr + 128;                       //     768 f
  float* bias_t   = bias_h + 768;                        //     768 f
  float* slot1    = bias_t + 768;                        // 1474560 f
  float* slot2    = slot1 + 1474560;                     // 2457600 f
  float* slot3    = slot2 + 2457600;                     // 1179648 f

  float* ent_att = slot1;
  float* ht_att  = slot2;
  short* Ars     = (short*)slot1;                        // 76*48*512 = 1867776 s
  short* Ahs     = (short*)slot2;                        // 1867776 s
  short* Ats     = Ahs + (size_t)MG * 48 * 512;          // 1867776 s
  short* Wfh     = (short*)slot3;                        // 96*24*512 = 1179648 s
  short* Wft     = Wfh + (size_t)96 * 24 * 512;          // 1179648 s
  short* Wt      = (short*)slot1;                        // 6291456 s (after k_head)

  k_detect<<<1, 256, 0, stream>>>((const unsigned int*)mmask, flag);
  k_ent_emb<<<B * E, 256, 0, stream>>>(seq, midx, mmask, ent_emb, flag);
  k_ent_att<<<B * E * H, 256, 0, stream>>>(att, midx, mmask, ent_att, flag);
  k_ht_att<<<B * P, 256, 0, stream>>>(ent_att, hts, ht_att);
  k_rs<<<dim3((P + 63) / 64, D / 64, B), 256, 0, stream>>>(ht_att, seq, Ars, flag);
  k_prep_ahs<<<dim3(MG, 2), 256, 0, stream>>>(ent_emb, hts, Ahs, Ats, Ars);
  k_prep_w<<<dim3(96, 2), 256, 0, stream>>>(headW, headb, tailW, tailb,
                                            Wfh, Wft, bias_h, bias_t, flag);
  k_head_mfma<<<dim3(19, 6, 2), 256, 0, stream>>>(Ahs, Ats, Ars, Wfh, Wft,
                                                  bias_h, bias_t, hz, tz);
  k_transpose_w<<<dim3(256, 12), 256, 0, stream>>>(bilW, Wt, flag);
  k_zero_logits<<<(N * NL + 255) / 256, 256, 0, stream>>>(logits_f);
  k_logits_mfma<<<dim3(12, (N + 127) / 128), 256, 0, stream>>>(hz, tz, Wt, logits_f);
  k_finish<<<(N * NL + 255) / 256, 256, 0, stream>>>(logits_f, bilb, d_out, flag);
  k_risk<<<RELS, 256, 0, stream>>>(logits_f, labels, pl, po, riskarr, flag);
  k_risk_sum<<<1, 128, 0, stream>>>(riskarr, d_out, flag);
}

// Round 5
// 526.428 us; speedup vs baseline: 3.0038x; 1.2366x over previous
//
#include <hip/hip_runtime.h>
#include <hip/hip_bf16.h>
#include <math.h>

typedef __hip_bfloat16 bf16;
typedef short s16x8 __attribute__((ext_vector_type(8)));
typedef float f32x16 __attribute__((ext_vector_type(16)));

// Problem constants (DocREModel)
constexpr int B = 4, H = 12, C = 1024, D = 768, E = 30, M = 8, P = 600;
constexpr int NL = 97, RELS = 96, EMB = 768;
constexpr int N = B * P;          // 2400 pairs
constexpr int MG = 76;            // 2432/32 row groups (N padded to 2432)
constexpr int MGB = 20;           // per-batch row groups for rs GEMM (608->640)

static __device__ __forceinline__ float b2f(bf16 x) { return __bfloat162float(x); }

// fast f32 -> bf16 bits (round-half-up; inputs finite)
static __device__ __forceinline__ short f2bfbits(float f) {
  unsigned u = __builtin_bit_cast(unsigned, f);
  return (short)((u + 0x8000u) >> 16);
}
static __device__ __forceinline__ float bf2f(short s) {
  return __builtin_bit_cast(float, ((unsigned)(unsigned short)s) << 16);
}

// dtype-agnostic load/store: BF=true -> buffer holds bf16, else float32
template <bool BF>
static __device__ __forceinline__ float ldf(const void* p, size_t i) {
  if (BF) return b2f(((const bf16*)p)[i]);
  return ((const float*)p)[i];
}
template <bool BF>
static __device__ __forceinline__ void stf(void* p, size_t i, float v) {
  if (BF) ((bf16*)p)[i] = __float2bfloat16(v);
  else    ((float*)p)[i] = v;
}

// ---------------------------------------------------------------------------
// Kernel 0: detect input dtype from mention_mask bit patterns.
// ---------------------------------------------------------------------------
__global__ __launch_bounds__(256) void k_detect(const unsigned int* __restrict__ mm,
                                                int* __restrict__ flag) {
  __shared__ int found;
  if (threadIdx.x == 0) found = 0;
  __syncthreads();
  for (int i = threadIdx.x; i < 480; i += 256) {
    unsigned int w = mm[i];
    if (w == 0x00003F80u || w == 0x3F803F80u) found = 1;
  }
  __syncthreads();
  if (threadIdx.x == 0) *flag = found;
}

// ---------------------------------------------------------------------------
// Kernel 1: ent_emb[b,e,d] = logsumexp over masked mentions of seq[b, idx, d]
// ---------------------------------------------------------------------------
struct EntEmbSmem { int sidx[M]; float smask[M]; };

template <bool BF>
static __device__ __forceinline__ void ent_emb_body(
    EntEmbSmem& s, const void* seq, const int* midx, const void* mmask,
    float* ent_emb) {
  int be = blockIdx.x;
  int b = be / E;
  if (threadIdx.x < M) {
    s.sidx[threadIdx.x] = midx[be * M + threadIdx.x] + 1;  // OFFSET
    s.smask[threadIdx.x] = ldf<BF>(mmask, be * M + threadIdx.x);
  }
  __syncthreads();
  for (int d = threadIdx.x; d < D; d += 256) {
    float v[M];
    float mx = -1e30f;
#pragma unroll
    for (int m = 0; m < M; m++) {
      v[m] = ldf<BF>(seq, ((size_t)(b * C + s.sidx[m])) * D + d);
      if (s.smask[m] != 0.0f) mx = fmaxf(mx, v[m]);
    }
    float sum = 0.f;
#pragma unroll
    for (int m = 0; m < M; m++)
      if (s.smask[m] != 0.0f) sum += expf(v[m] - mx);
    ent_emb[(size_t)be * D + d] = logf(sum) + mx;
  }
}

__global__ __launch_bounds__(256) void k_ent_emb(
    const void* seq, const int* midx, const void* mmask, float* ent_emb,
    const int* flag) {
  __shared__ EntEmbSmem s;
  if (*flag) ent_emb_body<true>(s, seq, midx, mmask, ent_emb);
  else       ent_emb_body<false>(s, seq, midx, mmask, ent_emb);
}

// ---------------------------------------------------------------------------
// Kernel 2: ent_att[b,e,h,c] = (sum_m mask*att[b,h,idx,c]) / cnt
// ---------------------------------------------------------------------------
struct EntAttSmem { int sidx[M]; float smask[M]; float sinv; };

template <bool BF>
static __device__ __forceinline__ void ent_att_body(
    EntAttSmem& s, const void* att, const int* midx, const void* mmask,
    float* ent_att) {
  int beh = blockIdx.x;
  int h = beh % H;
  int be = beh / H;
  int b = be / E;
  if (threadIdx.x < M) {
    s.sidx[threadIdx.x] = midx[be * M + threadIdx.x] + 1;
    s.smask[threadIdx.x] = ldf<BF>(mmask, be * M + threadIdx.x);
  }
  __syncthreads();
  if (threadIdx.x == 0) {
    float cnt = 0.f;
    for (int m = 0; m < M; m++) cnt += s.smask[m];
    s.sinv = 1.0f / cnt;
  }
  __syncthreads();
  for (int c = threadIdx.x; c < C; c += 256) {
    float sum = 0.f;
#pragma unroll
    for (int m = 0; m < M; m++)
      if (s.smask[m] != 0.0f)
        sum += ldf<BF>(att, (((size_t)b * H + h) * C + s.sidx[m]) * C + c);
    ent_att[((size_t)be * H + h) * C + c] = sum * s.sinv;
  }
}

__global__ __launch_bounds__(256) void k_ent_att(
    const void* att, const int* midx, const void* mmask, float* ent_att,
    const int* flag) {
  __shared__ EntAttSmem s;
  if (*flag) ent_att_body<true>(s, att, midx, mmask, ent_att);
  else       ent_att_body<false>(s, att, midx, mmask, ent_att);
}

// ---------------------------------------------------------------------------
// Kernel 3: ht_att row = normalize_c( mean_h( eA[h_i]*eA[t_i] ) ), written
// DIRECTLY as bf16 MFMA A-fragments (Aht, batch-local rows padded to 640):
// Aht[(((b*20 + mg)*64 + kc)*64 + half*32 + rr)*8 + tt] = row[c],
//   p = mg*32+rr, c = kc*16 + half*8 + tt.
// ---------------------------------------------------------------------------
__global__ __launch_bounds__(256) void k_ht_att(
    const float* __restrict__ ent_att, const int* __restrict__ hts,
    short* __restrict__ Aht) {
  int bp = blockIdx.x;
  int b = bp / P, p = bp % P;
  int hi = hts[bp * 2 + 0], ti = hts[bp * 2 + 1];
  const float* hA = ent_att + ((size_t)(b * E + hi)) * H * C;
  const float* tA = ent_att + ((size_t)(b * E + ti)) * H * C;
  float v[4];
  float loc = 0.f;
#pragma unroll
  for (int q = 0; q < 4; q++) {
    int c = threadIdx.x + q * 256;
    float s = 0.f;
#pragma unroll
    for (int h = 0; h < H; h++) s += hA[h * C + c] * tA[h * C + c];
    v[q] = s * (1.0f / H);
    loc += v[q];
  }
  __shared__ float red[256];
  red[threadIdx.x] = loc;
  __syncthreads();
  for (int off = 128; off > 0; off >>= 1) {
    if (threadIdx.x < off) red[threadIdx.x] += red[threadIdx.x + off];
    __syncthreads();
  }
  float inv = 1.0f / (red[0] + 1e-5f);
  int mg = p >> 5, rr = p & 31;
#pragma unroll
  for (int q = 0; q < 4; q++) {
    int c = threadIdx.x + q * 256;
    int kc = c >> 4, half = (c >> 3) & 1, tt = c & 7;
    Aht[((((size_t)(b * MGB + mg)) * 64 + kc) * 64 + half * 32 + rr) * 8 + tt] =
        f2bfbits(v[q] * inv);
  }
}

// ---------------------------------------------------------------------------
// Kernel 4a: pack seq into B-fragment order (bf16) for the rs GEMM; also
// zeroes the Aht pad rows (mg=18 rr>=24, mg=19 all). grid (64 kc, 4 b).
// Sf[(((b*64+kc)*24 + cg)*64 + lane)*8 + tt] = seq[b][kc*16+(lane>>5)*8+tt][cg*32+(lane&31)]
// ---------------------------------------------------------------------------
struct PrepSeqSmem { short Ss[16][776]; };

template <bool BF>
static __device__ __forceinline__ void prep_seq_body(
    PrepSeqSmem& sm, const void* seq, short* Sf, short* Aht) {
  int kc = blockIdx.x, b = blockIdx.y;
  int t = threadIdx.x;
  for (int e = t; e < 16 * D; e += 256) {
    int kk = e / D, c = e % D;
    sm.Ss[kk][c] = f2bfbits(ldf<BF>(seq, ((size_t)(b * C + kc * 16 + kk)) * D + c));
  }
  __syncthreads();
  int lane = t & 63, cg0 = t >> 6;
  int rr = lane & 31, half = lane >> 5;
#pragma unroll
  for (int q = 0; q < 6; q++) {
    int cg = cg0 + q * 4;
    int col = cg * 32 + rr;
    s16x8 v;
#pragma unroll
    for (int tt = 0; tt < 8; tt++) v[tt] = sm.Ss[half * 8 + tt][col];
    *(s16x8*)(Sf + ((((size_t)(b * 64 + kc)) * 24 + cg) * 64 + lane) * 8) = v;
  }
  if (t < 64) {
    s16x8 z = {0, 0, 0, 0, 0, 0, 0, 0};
    if ((t & 31) >= 24)
      *(s16x8*)(Aht + ((((size_t)(b * MGB + 18)) * 64 + kc) * 64 + t) * 8) = z;
    *(s16x8*)(Aht + ((((size_t)(b * MGB + 19)) * 64 + kc) * 64 + t) * 8) = z;
  }
}

__global__ __launch_bounds__(256) void k_prep_seq(
    const void* seq, short* Sf, short* Aht, const int* flag) {
  __shared__ PrepSeqSmem sm;
  if (*flag) prep_seq_body<true>(sm, seq, Sf, Aht);
  else       prep_seq_body<false>(sm, seq, Sf, Aht);
}

// ---------------------------------------------------------------------------
// Kernel 4b: rs = ht_att @ seq via MFMA 32x32x16 bf16, zero LDS / barriers.
// grid (10 mt, 6 nt, 4 b), 4 waves: wave = 32 rows x 64 cols, K=1024=64 chunks.
// Epilogue scatters bf16 into Ars (head-GEMM A-fragment layout, global rows).
// ---------------------------------------------------------------------------
__global__ __launch_bounds__(256) void k_rs_mfma(
    const short* __restrict__ Aht, const short* __restrict__ Sf,
    short* __restrict__ Ars) {
  int mt = blockIdx.x, nt = blockIdx.y, b = blockIdx.z;
  int t = threadIdx.x, w = t >> 6, lane = t & 63;
  int half = lane >> 5, r = lane & 31;
  int wm = w >> 1, wn = w & 1;
  int mg = mt * 2 + wm;          // 0..19
  int cg0 = nt * 4 + wn * 2;     // 0..22, 2 cg per wave

  f32x16 acc[2];
#pragma unroll
  for (int j = 0; j < 2; j++)
#pragma unroll
    for (int e = 0; e < 16; e++) acc[j][e] = 0.f;

  const short* abase = Aht + (((size_t)(b * MGB + mg)) * 64 * 64 + lane) * 8;
  const short* bbase = Sf + ((((size_t)(b * 64)) * 24 + cg0) * 64 + lane) * 8;

#pragma unroll 4
  for (int kc = 0; kc < 64; kc++) {
    s16x8 a  = *(const s16x8*)(abase + (size_t)kc * 64 * 8);
    s16x8 b0 = *(const s16x8*)(bbase + ((size_t)kc * 24 + 0) * 64 * 8);
    s16x8 b1 = *(const s16x8*)(bbase + ((size_t)kc * 24 + 1) * 64 * 8);
    acc[0] = __builtin_amdgcn_mfma_f32_32x32x16_bf16(a, b0, acc[0], 0, 0, 0);
    acc[1] = __builtin_amdgcn_mfma_f32_32x32x16_bf16(a, b1, acc[1], 0, 0, 0);
  }

  // C/D: col = lane&31, row = (reg&3) + 8*(reg>>2) + 4*half
#pragma unroll
  for (int j = 0; j < 2; j++) {
    int col = (cg0 + j) * 32 + r;            // 0..767 (the rs feature index)
    int kcd = col >> 4, hd = (col >> 3) & 1, ttd = col & 7;
#pragma unroll
    for (int reg = 0; reg < 16; reg++) {
      int p = mg * 32 + (reg & 3) + 8 * (reg >> 2) + 4 * half;
      if (p < P) {
        int n = b * P + p;
        Ars[((((size_t)(n >> 5)) * 48 + kcd) * 64 + hd * 32 + (n & 31)) * 8 + ttd] =
            f2bfbits(acc[j][reg]);
      }
    }
  }
}

// ---------------------------------------------------------------------------
// Kernel 5a: build hs/ts halves of the head/tail A matrices in fragment order.
// Also zeroes the pad rows (mg=75) of Ars. grid (76, 2).
// ---------------------------------------------------------------------------
__global__ __launch_bounds__(256) void k_prep_ahs(
    const float* __restrict__ ent_emb, const int* __restrict__ hts,
    short* __restrict__ Ahs, short* __restrict__ Ats, short* __restrict__ Ars) {
  int mg = blockIdx.x, which = blockIdx.y;
  short* Adst = which ? Ats : Ahs;
  int t = threadIdx.x, lane = t & 63, kc0 = t >> 6;
  int rr = lane & 31, half = lane >> 5;
  int row = mg * 32 + rr;
  bool valid = row < N;
  size_t base = 0;
  if (valid) {
    int b = row / P, p = row % P;
    int e = hts[(b * P + p) * 2 + which];
    base = (size_t)(b * E + e) * D;
  }
#pragma unroll
  for (int q = 0; q < 12; q++) {
    int kc = kc0 + q * 4;
    s16x8 v = {0, 0, 0, 0, 0, 0, 0, 0};
    if (valid) {
      const float* p = ent_emb + base + kc * 16 + half * 8;
      float4 v0 = *(const float4*)p;
      float4 v1 = *(const float4*)(p + 4);
      v[0] = f2bfbits(v0.x); v[1] = f2bfbits(v0.y);
      v[2] = f2bfbits(v0.z); v[3] = f2bfbits(v0.w);
      v[4] = f2bfbits(v1.x); v[5] = f2bfbits(v1.y);
      v[6] = f2bfbits(v1.z); v[7] = f2bfbits(v1.w);
    }
    *(s16x8*)(Adst + (((size_t)mg * 48 + kc) * 64 + lane) * 8) = v;
    if (which == 0 && mg == MG - 1) {
      s16x8 z = {0, 0, 0, 0, 0, 0, 0, 0};
      *(s16x8*)(Ars + (((size_t)(MG - 1) * 48 + kc) * 64 + lane) * 8) = z;
    }
  }
}

// ---------------------------------------------------------------------------
// Kernel 5b: pack head_W / tail_W into B-fragment order (bf16) + biases f32.
// ---------------------------------------------------------------------------
struct PrepWSmem { short Ws[16][776]; };

template <bool BF>
static __device__ __forceinline__ void prep_w_body(
    PrepWSmem& sm, const void* headW, const void* headb,
    const void* tailW, const void* tailb,
    short* Wfh, short* Wft, float* bias_h, float* bias_t) {
  int kc = blockIdx.x, which = blockIdx.y;
  const void* W = which ? tailW : headW;
  short* Wf = which ? Wft : Wfh;
  int t = threadIdx.x;
  for (int e = t; e < 16 * EMB; e += 256) {
    int kk = e / EMB, c = e % EMB;
    sm.Ws[kk][c] = f2bfbits(ldf<BF>(W, (size_t)(kc * 16 + kk) * EMB + c));
  }
  __syncthreads();
  int lane = t & 63, cg0 = t >> 6;
  int rr = lane & 31, half = lane >> 5;
#pragma unroll
  for (int q = 0; q < 6; q++) {
    int cg = cg0 + q * 4;
    int col = cg * 32 + rr;
    s16x8 v;
#pragma unroll
    for (int tt = 0; tt < 8; tt++) v[tt] = sm.Ws[half * 8 + tt][col];
    *(s16x8*)(Wf + (((size_t)kc * 24 + cg) * 64 + lane) * 8) = v;
  }
  if (kc == 0) {
    const void* bsrc = which ? tailb : headb;
    float* bdst = which ? bias_t : bias_h;
    for (int c = t; c < EMB; c += 256) bdst[c] = ldf<BF>(bsrc, c);
  }
}

__global__ __launch_bounds__(256) void k_prep_w(
    const void* headW, const void* headb, const void* tailW, const void* tailb,
    short* Wfh, short* Wft, float* bias_h, float* bias_t, const int* flag) {
  __shared__ PrepWSmem sm;
  if (*flag) prep_w_body<true>(sm, headW, headb, tailW, tailb, Wfh, Wft, bias_h, bias_t);
  else       prep_w_body<false>(sm, headW, headb, tailW, tailb, Wfh, Wft, bias_h, bias_t);
}

// ---------------------------------------------------------------------------
// Kernel 5c: hz/tz = tanh(A @ W + bias) via MFMA, output bf16.
// grid (19, 6, 2), 4 waves (2x2), wave = 64x64 tile, K = 1536 = 96 chunks.
// ---------------------------------------------------------------------------
__global__ __launch_bounds__(256) void k_head_mfma(
    const short* __restrict__ Ahs, const short* __restrict__ Ats,
    const short* __restrict__ Ars,
    const short* __restrict__ Wfh, const short* __restrict__ Wft,
    const float* __restrict__ bias_h, const float* __restrict__ bias_t,
    short* __restrict__ hz, short* __restrict__ tz) {
  int mt = blockIdx.x, nt = blockIdx.y, which = blockIdx.z;
  const short* Ahead = which ? Ats : Ahs;
  const short* Wf = which ? Wft : Wfh;
  const float* bias = which ? bias_t : bias_h;
  short* out = which ? tz : hz;

  int t = threadIdx.x, w = t >> 6, lane = t & 63;
  int half = lane >> 5, r = lane & 31;
  int wm = w >> 1, wn = w & 1;
  int mg0 = mt * 4 + wm * 2;
  int cg0 = nt * 4 + wn * 2;

  f32x16 acc[2][2];
#pragma unroll
  for (int i = 0; i < 2; i++)
#pragma unroll
    for (int j = 0; j < 2; j++)
#pragma unroll
      for (int e = 0; e < 16; e++) acc[i][j][e] = 0.f;

#pragma unroll 4
  for (int kc = 0; kc < 48; kc++) {
    s16x8 a0 = *(const s16x8*)(Ahead + (((size_t)(mg0 + 0) * 48 + kc) * 64 + lane) * 8);
    s16x8 a1 = *(const s16x8*)(Ahead + (((size_t)(mg0 + 1) * 48 + kc) * 64 + lane) * 8);
    s16x8 b0 = *(const s16x8*)(Wf + (((size_t)kc * 24 + cg0 + 0) * 64 + lane) * 8);
    s16x8 b1 = *(const s16x8*)(Wf + (((size_t)kc * 24 + cg0 + 1) * 64 + lane) * 8);
    acc[0][0] = __builtin_amdgcn_mfma_f32_32x32x16_bf16(a0, b0, acc[0][0], 0, 0, 0);
    acc[0][1] = __builtin_amdgcn_mfma_f32_32x32x16_bf16(a0, b1, acc[0][1], 0, 0, 0);
    acc[1][0] = __builtin_amdgcn_mfma_f32_32x32x16_bf16(a1, b0, acc[1][0], 0, 0, 0);
    acc[1][1] = __builtin_amdgcn_mfma_f32_32x32x16_bf16(a1, b1, acc[1][1], 0, 0, 0);
  }
#pragma unroll 4
  for (int kc = 0; kc < 48; kc++) {
    s16x8 a0 = *(const s16x8*)(Ars + (((size_t)(mg0 + 0) * 48 + kc) * 64 + lane) * 8);
    s16x8 a1 = *(const s16x8*)(Ars + (((size_t)(mg0 + 1) * 48 + kc) * 64 + lane) * 8);
    s16x8 b0 = *(const s16x8*)(Wf + (((size_t)(kc + 48) * 24 + cg0 + 0) * 64 + lane) * 8);
    s16x8 b1 = *(const s16x8*)(Wf + (((size_t)(kc + 48) * 24 + cg0 + 1) * 64 + lane) * 8);
    acc[0][0] = __builtin_amdgcn_mfma_f32_32x32x16_bf16(a0, b0, acc[0][0], 0, 0, 0);
    acc[0][1] = __builtin_amdgcn_mfma_f32_32x32x16_bf16(a0, b1, acc[0][1], 0, 0, 0);
    acc[1][0] = __builtin_amdgcn_mfma_f32_32x32x16_bf16(a1, b0, acc[1][0], 0, 0, 0);
    acc[1][1] = __builtin_amdgcn_mfma_f32_32x32x16_bf16(a1, b1, acc[1][1], 0, 0, 0);
  }

#pragma unroll
  for (int i = 0; i < 2; i++) {
    int rowbase = (mg0 + i) * 32 + 4 * half;
#pragma unroll
    for (int j = 0; j < 2; j++) {
      int col = (cg0 + j) * 32 + r;
      float bv = bias[col];
#pragma unroll
      for (int reg = 0; reg < 16; reg++) {
        int n = rowbase + (reg & 3) + 8 * (reg >> 2);
        if (n < N) out[(size_t)n * EMB + col] = f2bfbits(tanhf(acc[i][j][reg] + bv));
      }
    }
  }
}

// ---------------------------------------------------------------------------
// Kernel 6a: pre-pack bil_W into MFMA B-fragment order, bf16.
// ---------------------------------------------------------------------------
struct TwSmem { float Ws[16][100]; };

template <bool BF>
static __device__ __forceinline__ void transpose_w_body(
    TwSmem& sm, const void* bilW, short* Wt) {
  int s16i = blockIdx.x, kb = blockIdx.y;
  int t = threadIdx.x;
  size_t kbase = (size_t)kb * 4096 + s16i * 16;
  for (int e = t; e < 16 * NL; e += 256) {
    int rr = e / NL, l = e % NL;
    sm.Ws[rr][l] = ldf<BF>(bilW, (kbase + rr) * NL + l);
  }
  __syncthreads();
  int c = t >> 6, lane = t & 63;
  int half = lane >> 5, col = lane & 31;
  int label = c * 32 + col;
  s16x8 v;
#pragma unroll
  for (int tt = 0; tt < 8; tt++) {
    float x = (label < NL) ? sm.Ws[half * 8 + tt][label] : 0.f;
    v[tt] = f2bfbits(x);
  }
  size_t off = ((((size_t)kb * 256 + s16i) * 4 + c) * 64 + lane) * 8;
  *(s16x8*)(Wt + off) = v;
}

__global__ __launch_bounds__(256) void k_transpose_w(
    const void* bilW, short* Wt, const int* flag) {
  __shared__ TwSmem sm;
  if (*flag) transpose_w_body<true>(sm, bilW, Wt);
  else       transpose_w_body<false>(sm, bilW, Wt);
}

// ---------------------------------------------------------------------------
// Kernel 6b: zero logits accumulator
// ---------------------------------------------------------------------------
__global__ __launch_bounds__(256) void k_zero_logits(float* __restrict__ logits_f) {
  int idx = blockIdx.x * 256 + threadIdx.x;
  if (idx < N * NL) logits_f[idx] = 0.f;
}

// ---------------------------------------------------------------------------
// Kernel 6c: bilinear logits via MFMA 32x32x16 bf16, A generated on the fly.
// hz/tz are bf16 now.
// ---------------------------------------------------------------------------
__global__ __launch_bounds__(256) void k_logits_mfma(
    const short* __restrict__ hz, const short* __restrict__ tz,
    const short* __restrict__ Wt, float* __restrict__ logits_f) {
  int kb = blockIdx.x;
  int mb = blockIdx.y;
  int t = threadIdx.x;
  int w = t >> 6, lane = t & 63;
  int half = lane >> 5, r = lane & 31;
  int nb = mb * 128;

  __shared__ float hzs[128][65];
  {
    int row = t >> 1;
    int col0 = (t & 1) * 32;
    int n = nb + row;
#pragma unroll
    for (int q = 0; q < 4; q++) {
      float vv[8] = {0.f, 0.f, 0.f, 0.f, 0.f, 0.f, 0.f, 0.f};
      if (n < N) {
        s16x8 v = *(const s16x8*)(hz + (size_t)n * EMB + kb * 64 + col0 + q * 8);
#pragma unroll
        for (int tt = 0; tt < 8; tt++) vv[tt] = bf2f(v[tt]);
      }
#pragma unroll
      for (int tt = 0; tt < 8; tt++) hzs[row][col0 + q * 8 + tt] = vv[tt];
    }
  }
  float tzr[4][8];
  {
    int n = nb + w * 32 + r;
#pragma unroll
    for (int q4 = 0; q4 < 4; q4++) {
      s16x8 v = {0, 0, 0, 0, 0, 0, 0, 0};
      if (n < N) v = *(const s16x8*)(tz + (size_t)n * EMB + kb * 64 + q4 * 16 + half * 8);
#pragma unroll
      for (int tt = 0; tt < 8; tt++) tzr[q4][tt] = bf2f(v[tt]);
    }
  }
  __syncthreads();

  f32x16 acc[4];
#pragma unroll
  for (int c = 0; c < 4; c++)
#pragma unroll
    for (int e = 0; e < 16; e++) acc[c][e] = 0.f;

  const int wrow = w * 32 + r;
  const short* wbase = Wt + (((size_t)kb * 256) * 4) * 64 * 8 + (size_t)lane * 8;

#pragma unroll 2
  for (int i = 0; i < 64; i++) {
    float hv = hzs[wrow][i];
#pragma unroll
    for (int q4 = 0; q4 < 4; q4++) {
      s16x8 af;
#pragma unroll
      for (int tt = 0; tt < 8; tt++) af[tt] = f2bfbits(hv * tzr[q4][tt]);
      int s16i = i * 4 + q4;
#pragma unroll
      for (int c = 0; c < 4; c++) {
        s16x8 bf = *(const s16x8*)(wbase + ((size_t)s16i * 4 + c) * 64 * 8);
        acc[c] = __builtin_amdgcn_mfma_f32_32x32x16_bf16(af, bf, acc[c], 0, 0, 0);
      }
    }
  }

#pragma unroll
  for (int c = 0; c < 4; c++) {
    int label = c * 32 + r;
    if (label < NL) {
#pragma unroll
      for (int reg = 0; reg < 16; reg++) {
        int row = (reg & 3) + 8 * (reg >> 2) + 4 * half;
        int n = nb + w * 32 + row;
        if (n < N) atomicAdd(&logits_f[(size_t)n * NL + label], acc[c][reg]);
      }
    }
  }
}

// ---------------------------------------------------------------------------
// Kernel 6d: logits += bias; emit output logits in out dtype
// ---------------------------------------------------------------------------
template <bool BF>
static __device__ __forceinline__ void finish_body(
    float* logits_f, const void* bilb, void* out) {
  int idx = blockIdx.x * 256 + threadIdx.x;
  if (idx >= N * NL) return;
  int l = idx % NL;
  float s = logits_f[idx] + ldf<BF>(bilb, l);
  logits_f[idx] = s;
  stf<BF>(out, (size_t)idx + 1, s);  // out[0] = risk, out[1..] = logits
}

__global__ __launch_bounds__(256) void k_finish(
    float* logits_f, const void* bilb, void* out, const int* flag) {
  if (*flag) finish_body<true>(logits_f, bilb, out);
  else       finish_body<false>(logits_f, bilb, out);
}

// ---------------------------------------------------------------------------
// Kernel 7: per-relation PU risk. grid = RELS blocks.
// ---------------------------------------------------------------------------
struct RiskSmem { float red[5][256]; };

template <bool BF>
static __device__ __forceinline__ void risk_body(
    RiskSmem& sm, const float* logits_f, const int* labels,
    const void* priors_l, const void* priors_o, float* riskarr) {
  int r = blockIdx.x;  // 0..95
  int t = threadIdx.x;
  float s_neg = 0.f, s_pp = 0.f, s_pn = 0.f, c_neg = 0.f, c_pos = 0.f;
  for (int n = t; n < N; n += 256) {
    float sc = logits_f[(size_t)n * NL + (r + 1)] - logits_f[(size_t)n * NL];
    bool pos = labels[(size_t)n * NL + (r + 1)] == 1;
    float ln = 0.25f * (sc + 1.f) * (sc + 1.f);  // sign=-1
    float lp = 0.25f * (sc - 1.f) * (sc - 1.f);  // sign=+1
    if (pos) { c_pos += 1.f; s_pp += lp; s_pn += ln; }
    else     { c_neg += 1.f; s_neg += ln; }
  }
  sm.red[0][t] = s_neg; sm.red[1][t] = s_pp; sm.red[2][t] = s_pn;
  sm.red[3][t] = c_neg; sm.red[4][t] = c_pos;
  __syncthreads();
  for (int off = 128; off > 0; off >>= 1) {
    if (t < off) {
#pragma unroll
      for (int q = 0; q < 5; q++) sm.red[q][t] += sm.red[q][t + off];
    }
    __syncthreads();
  }
  if (t == 0) {
    float sq_neg   = sm.red[3][0] > 0.f ? sm.red[0][0] / fmaxf(sm.red[3][0], 1.f) : 0.f;
    float sq_pos_p = sm.red[4][0] > 0.f ? sm.red[1][0] / fmaxf(sm.red[4][0], 1.f) : 0.f;
    float sq_pos_n = sm.red[4][0] > 0.f ? sm.red[2][0] / fmaxf(sm.red[4][0], 1.f) : 0.f;
    float po = ldf<BF>(priors_o, r), pl = ldf<BF>(priors_l, r);
    float weight = sqrtf((1.f - po) / po);
    float pu = (po - pl) / (1.f - pl);
    float risk1 = (1.f - po) / (1.f - pu) * sq_neg - (pu - pu * po) / (1.f - pu) * sq_pos_n;
    float risk2 = po * sq_pos_p * weight;
    riskarr[r] = (risk1 < 0.f) ? -risk1 : (risk1 + risk2);  // BETA=0, GAMMA=1
  }
}

__global__ __launch_bounds__(256) void k_risk(
    const float* logits_f, const int* labels, const void* priors_l,
    const void* priors_o, float* riskarr, const int* flag) {
  __shared__ RiskSmem sm;
  if (*flag) risk_body<true>(sm, logits_f, labels, priors_l, priors_o, riskarr);
  else       risk_body<false>(sm, logits_f, labels, priors_l, priors_o, riskarr);
}

__global__ __launch_bounds__(128) void k_risk_sum(
    const float* __restrict__ riskarr, void* out, const int* flag) {
  __shared__ float red[128];
  int t = threadIdx.x;
  red[t] = (t < RELS) ? riskarr[t] : 0.f;
  __syncthreads();
  for (int off = 64; off > 0; off >>= 1) {
    if (t < off) red[t] += red[t + off];
    __syncthreads();
  }
  if (t == 0) {
    if (*flag) stf<true>(out, 0, red[0]);
    else       stf<false>(out, 0, red[0]);
  }
}

// ---------------------------------------------------------------------------
extern "C" void kernel_launch(void* const* d_in, const int* in_sizes, int n_in,
                              void* d_out, int out_size, void* d_ws, size_t ws_size,
                              hipStream_t stream) {
  const void* seq    = d_in[0];
  const void* att    = d_in[1];
  const int*  midx   = (const int*)d_in[2];
  const void* mmask  = d_in[3];
  const int*  hts    = (const int*)d_in[4];
  const int*  labels = (const int*)d_in[5];
  const void* pl     = d_in[6];
  const void* po     = d_in[7];
  const void* headW  = d_in[8];
  const void* headb  = d_in[9];
  const void* tailW  = d_in[10];
  const void* tailb  = d_in[11];
  const void* bilW   = d_in[12];
  const void* bilb   = d_in[13];

  // Workspace layout (floats after 64B flag); ~38.3 MB total.
  // regionA = [ent_att | Aht | Sf] (4,358,144 f):
  //   ent_att dead after k_ht_att; Aht/Sf dead after k_rs_mfma.
  //   Ars  aliases regionA start (written k_rs_mfma/k_prep_ahs, after ent_att dead)
  //   Wt   aliases regionA start (written k_transpose_w AFTER k_head_mfma,
  //        when Ars/Aht/Sf are all dead); extent 3,145,728 f < regionA.
  int* flag = (int*)d_ws;
  float* w = (float*)d_ws + 16;
  float* ent_emb  = w;                                   //    92,160 f
  short* hz       = (short*)(ent_emb + (size_t)B * E * D); // 1,843,200 s = 921,600 f
  short* tz       = hz + (size_t)N * EMB;                //   921,600 f
  float* logits_f = (float*)(tz + (size_t)N * EMB);      //   232,800 f
  float* riskarr  = logits_f + (size_t)N * NL;           //       128 f
  float* bias_h   = riskarr + 128;                       //       768 f
  float* bias_t   = bias_h + 768;                        //       768 f
  float* regionA  = bias_t + 768;                        // 4,358,144 f
  float* ent_att  = regionA;                             // 1,474,560 f
  short* Aht      = (short*)(regionA + 1474560);         // 2,621,440 s
  short* Sf       = Aht + (size_t)B * MGB * 64 * 512;    // 3,145,728 s
  short* Ars      = (short*)regionA;                     // 1,867,776 s (alias)
  short* Wt       = (short*)regionA;                     // 6,291,456 s (alias, late)
  float* after    = regionA + 4358144;
  short* Ahs      = (short*)after;                       // 1,867,776 s
  short* Ats      = Ahs + (size_t)MG * 48 * 512;         // 1,867,776 s
  short* Wfh      = Ats + (size_t)MG * 48 * 512;         // 1,179,648 s
  short* Wft      = Wfh + (size_t)96 * 24 * 512;         // 1,179,648 s

  k_detect<<<1, 256, 0, stream>>>((const unsigned int*)mmask, flag);
  k_ent_emb<<<B * E, 256, 0, stream>>>(seq, midx, mmask, ent_emb, flag);
  k_ent_att<<<B * E * H, 256, 0, stream>>>(att, midx, mmask, ent_att, flag);
  k_ht_att<<<B * P, 256, 0, stream>>>(ent_att, hts, Aht);
  k_prep_seq<<<dim3(64, B), 256, 0, stream>>>(seq, Sf, Aht, flag);
  k_rs_mfma<<<dim3(10, 6, B), 256, 0, stream>>>(Aht, Sf, Ars);
  k_prep_ahs<<<dim3(MG, 2), 256, 0, stream>>>(ent_emb, hts, Ahs, Ats, Ars);
  k_prep_w<<<dim3(96, 2), 256, 0, stream>>>(headW, headb, tailW, tailb,
                                            Wfh, Wft, bias_h, bias_t, flag);
  k_head_mfma<<<dim3(19, 6, 2), 256, 0, stream>>>(Ahs, Ats, Ars, Wfh, Wft,
                                                  bias_h, bias_t, hz, tz);
  k_transpose_w<<<dim3(256, 12), 256, 0, stream>>>(bilW, Wt, flag);
  k_zero_logits<<<(N * NL + 255) / 256, 256, 0, stream>>>(logits_f);
  k_logits_mfma<<<dim3(12, (N + 127) / 128), 256, 0, stream>>>(hz, tz, Wt, logits_f);
  k_finish<<<(N * NL + 255) / 256, 256, 0, stream>>>(logits_f, bilb, d_out, flag);
  k_risk<<<RELS, 256, 0, stream>>>(logits_f, labels, pl, po, riskarr, flag);
  k_risk_sum<<<1, 128, 0, stream>>>(riskarr, d_out, flag);
}

// Round 6
// 503.251 us; speedup vs baseline: 3.1421x; 1.0461x over previous
//
#include <hip/hip_runtime.h>
#include <hip/hip_bf16.h>
#include <math.h>

typedef __hip_bfloat16 bf16;
typedef short s16x8 __attribute__((ext_vector_type(8)));
typedef float f32x16 __attribute__((ext_vector_type(16)));

// Problem constants (DocREModel)
constexpr int B = 4, H = 12, C = 1024, D = 768, E = 30, M = 8, P = 600;
constexpr int NL = 97, RELS = 96, EMB = 768;
constexpr int N = B * P;          // 2400 pairs
constexpr int MG = 76;            // 2432/32 row groups (N padded to 2432)
constexpr int MGB = 20;           // per-batch row groups for rs GEMM (608->640)

static __device__ __forceinline__ float b2f(bf16 x) { return __bfloat162float(x); }

// fast f32 -> bf16 bits (round-half-up; inputs finite)
static __device__ __forceinline__ short f2bfbits(float f) {
  unsigned u = __builtin_bit_cast(unsigned, f);
  return (short)((u + 0x8000u) >> 16);
}
static __device__ __forceinline__ float bf2f(short s) {
  return __builtin_bit_cast(float, ((unsigned)(unsigned short)s) << 16);
}

// dtype-agnostic load/store: BF=true -> buffer holds bf16, else float32
template <bool BF>
static __device__ __forceinline__ float ldf(const void* p, size_t i) {
  if (BF) return b2f(((const bf16*)p)[i]);
  return ((const float*)p)[i];
}
template <bool BF>
static __device__ __forceinline__ void stf(void* p, size_t i, float v) {
  if (BF) ((bf16*)p)[i] = __float2bfloat16(v);
  else    ((float*)p)[i] = v;
}

// ---------------------------------------------------------------------------
// Kernel 0: detect input dtype from mention_mask bit patterns.
// ---------------------------------------------------------------------------
__global__ __launch_bounds__(256) void k_detect(const unsigned int* __restrict__ mm,
                                                int* __restrict__ flag) {
  __shared__ int found;
  if (threadIdx.x == 0) found = 0;
  __syncthreads();
  for (int i = threadIdx.x; i < 480; i += 256) {
    unsigned int w = mm[i];
    if (w == 0x00003F80u || w == 0x3F803F80u) found = 1;
  }
  __syncthreads();
  if (threadIdx.x == 0) *flag = found;
}

// ---------------------------------------------------------------------------
// Kernel 1: ent_emb[b,e,d] = logsumexp over masked mentions of seq[b, idx, d]
// ---------------------------------------------------------------------------
struct EntEmbSmem { int sidx[M]; float smask[M]; };

template <bool BF>
static __device__ __forceinline__ void ent_emb_body(
    EntEmbSmem& s, const void* seq, const int* midx, const void* mmask,
    float* ent_emb) {
  int be = blockIdx.x;
  int b = be / E;
  if (threadIdx.x < M) {
    s.sidx[threadIdx.x] = midx[be * M + threadIdx.x] + 1;  // OFFSET
    s.smask[threadIdx.x] = ldf<BF>(mmask, be * M + threadIdx.x);
  }
  __syncthreads();
  for (int d = threadIdx.x; d < D; d += 256) {
    float v[M];
    float mx = -1e30f;
#pragma unroll
    for (int m = 0; m < M; m++) {
      v[m] = ldf<BF>(seq, ((size_t)(b * C + s.sidx[m])) * D + d);
      if (s.smask[m] != 0.0f) mx = fmaxf(mx, v[m]);
    }
    float sum = 0.f;
#pragma unroll
    for (int m = 0; m < M; m++)
      if (s.smask[m] != 0.0f) sum += expf(v[m] - mx);
    ent_emb[(size_t)be * D + d] = logf(sum) + mx;
  }
}

__global__ __launch_bounds__(256) void k_ent_emb(
    const void* seq, const int* midx, const void* mmask, float* ent_emb,
    const int* flag) {
  __shared__ EntEmbSmem s;
  if (*flag) ent_emb_body<true>(s, seq, midx, mmask, ent_emb);
  else       ent_emb_body<false>(s, seq, midx, mmask, ent_emb);
}

// ---------------------------------------------------------------------------
// Kernel 2: ent_att[b,e,h,c] = (sum_m mask*att[b,h,idx,c]) / cnt  (bf16 out)
// ---------------------------------------------------------------------------
struct EntAttSmem { int sidx[M]; float smask[M]; float sinv; };

template <bool BF>
static __device__ __forceinline__ void ent_att_body(
    EntAttSmem& s, const void* att, const int* midx, const void* mmask,
    short* ent_att) {
  int beh = blockIdx.x;
  int h = beh % H;
  int be = beh / H;
  int b = be / E;
  if (threadIdx.x < M) {
    s.sidx[threadIdx.x] = midx[be * M + threadIdx.x] + 1;
    s.smask[threadIdx.x] = ldf<BF>(mmask, be * M + threadIdx.x);
  }
  __syncthreads();
  if (threadIdx.x == 0) {
    float cnt = 0.f;
    for (int m = 0; m < M; m++) cnt += s.smask[m];
    s.sinv = 1.0f / cnt;
  }
  __syncthreads();
  for (int c = threadIdx.x; c < C; c += 256) {
    float sum = 0.f;
#pragma unroll
    for (int m = 0; m < M; m++)
      if (s.smask[m] != 0.0f)
        sum += ldf<BF>(att, (((size_t)b * H + h) * C + s.sidx[m]) * C + c);
    ent_att[((size_t)be * H + h) * C + c] = f2bfbits(sum * s.sinv);
  }
}

__global__ __launch_bounds__(256) void k_ent_att(
    const void* att, const int* midx, const void* mmask, short* ent_att,
    const int* flag) {
  __shared__ EntAttSmem s;
  if (*flag) ent_att_body<true>(s, att, midx, mmask, ent_att);
  else       ent_att_body<false>(s, att, midx, mmask, ent_att);
}

// ---------------------------------------------------------------------------
// Kernel 3: ht_att row = normalize_c( mean_h( eA[h_i]*eA[t_i] ) ), written
// DIRECTLY as bf16 MFMA A-fragments (Aht). ent_att is bf16; ushort2 loads.
// ---------------------------------------------------------------------------
__global__ __launch_bounds__(256) void k_ht_att(
    const short* __restrict__ ent_att, const int* __restrict__ hts,
    short* __restrict__ Aht) {
  int bp = blockIdx.x;
  int b = bp / P, p = bp % P;
  int hi = hts[bp * 2 + 0], ti = hts[bp * 2 + 1];
  const short* hA = ent_att + ((size_t)(b * E + hi)) * H * C;
  const short* tA = ent_att + ((size_t)(b * E + ti)) * H * C;
  float v[2][2];
  float loc = 0.f;
#pragma unroll
  for (int q = 0; q < 2; q++) {
    int c = q * 512 + threadIdx.x * 2;
    float s0 = 0.f, s1 = 0.f;
#pragma unroll
    for (int h = 0; h < H; h++) {
      ushort2 a = *(const ushort2*)(hA + h * C + c);
      ushort2 t2 = *(const ushort2*)(tA + h * C + c);
      s0 += bf2f((short)a.x) * bf2f((short)t2.x);
      s1 += bf2f((short)a.y) * bf2f((short)t2.y);
    }
    v[q][0] = s0 * (1.0f / H);
    v[q][1] = s1 * (1.0f / H);
    loc += v[q][0] + v[q][1];
  }
  __shared__ float red[256];
  red[threadIdx.x] = loc;
  __syncthreads();
  for (int off = 128; off > 0; off >>= 1) {
    if (threadIdx.x < off) red[threadIdx.x] += red[threadIdx.x + off];
    __syncthreads();
  }
  float inv = 1.0f / (red[0] + 1e-5f);
  int mg = p >> 5, rr = p & 31;
#pragma unroll
  for (int q = 0; q < 2; q++) {
    int c = q * 512 + threadIdx.x * 2;
    int kc = c >> 4, half = (c >> 3) & 1, tt = c & 7;
    short* dst =
        Aht + ((((size_t)(b * MGB + mg)) * 64 + kc) * 64 + half * 32 + rr) * 8 + tt;
    dst[0] = f2bfbits(v[q][0] * inv);
    dst[1] = f2bfbits(v[q][1] * inv);
  }
}

// ---------------------------------------------------------------------------
// Kernel 4a: pack seq into B-fragment order (bf16) for the rs GEMM; also
// zeroes the Aht pad rows. grid (64 kc, 4 b).
// ---------------------------------------------------------------------------
struct PrepSeqSmem { short Ss[16][776]; };

template <bool BF>
static __device__ __forceinline__ void prep_seq_body(
    PrepSeqSmem& sm, const void* seq, short* Sf, short* Aht) {
  int kc = blockIdx.x, b = blockIdx.y;
  int t = threadIdx.x;
  for (int e = t; e < 16 * D; e += 256) {
    int kk = e / D, c = e % D;
    sm.Ss[kk][c] = f2bfbits(ldf<BF>(seq, ((size_t)(b * C + kc * 16 + kk)) * D + c));
  }
  __syncthreads();
  int lane = t & 63, cg0 = t >> 6;
  int rr = lane & 31, half = lane >> 5;
#pragma unroll
  for (int q = 0; q < 6; q++) {
    int cg = cg0 + q * 4;
    int col = cg * 32 + rr;
    s16x8 v;
#pragma unroll
    for (int tt = 0; tt < 8; tt++) v[tt] = sm.Ss[half * 8 + tt][col];
    *(s16x8*)(Sf + ((((size_t)(b * 64 + kc)) * 24 + cg) * 64 + lane) * 8) = v;
  }
  if (t < 64) {
    s16x8 z = {0, 0, 0, 0, 0, 0, 0, 0};
    if ((t & 31) >= 24)
      *(s16x8*)(Aht + ((((size_t)(b * MGB + 18)) * 64 + kc) * 64 + t) * 8) = z;
    *(s16x8*)(Aht + ((((size_t)(b * MGB + 19)) * 64 + kc) * 64 + t) * 8) = z;
  }
}

__global__ __launch_bounds__(256) void k_prep_seq(
    const void* seq, short* Sf, short* Aht, const int* flag) {
  __shared__ PrepSeqSmem sm;
  if (*flag) prep_seq_body<true>(sm, seq, Sf, Aht);
  else       prep_seq_body<false>(sm, seq, Sf, Aht);
}

// ---------------------------------------------------------------------------
// Kernel 4b: rs = ht_att @ seq via MFMA 32x32x16 bf16, zero LDS / barriers.
// ---------------------------------------------------------------------------
__global__ __launch_bounds__(256) void k_rs_mfma(
    const short* __restrict__ Aht, const short* __restrict__ Sf,
    short* __restrict__ Ars) {
  int mt = blockIdx.x, nt = blockIdx.y, b = blockIdx.z;
  int t = threadIdx.x, w = t >> 6, lane = t & 63;
  int half = lane >> 5, r = lane & 31;
  int wm = w >> 1, wn = w & 1;
  int mg = mt * 2 + wm;          // 0..19
  int cg0 = nt * 4 + wn * 2;     // 0..22, 2 cg per wave

  f32x16 acc[2];
#pragma unroll
  for (int j = 0; j < 2; j++)
#pragma unroll
    for (int e = 0; e < 16; e++) acc[j][e] = 0.f;

  const short* abase = Aht + (((size_t)(b * MGB + mg)) * 64 * 64 + lane) * 8;
  const short* bbase = Sf + ((((size_t)(b * 64)) * 24 + cg0) * 64 + lane) * 8;

#pragma unroll 4
  for (int kc = 0; kc < 64; kc++) {
    s16x8 a  = *(const s16x8*)(abase + (size_t)kc * 64 * 8);
    s16x8 b0 = *(const s16x8*)(bbase + ((size_t)kc * 24 + 0) * 64 * 8);
    s16x8 b1 = *(const s16x8*)(bbase + ((size_t)kc * 24 + 1) * 64 * 8);
    acc[0] = __builtin_amdgcn_mfma_f32_32x32x16_bf16(a, b0, acc[0], 0, 0, 0);
    acc[1] = __builtin_amdgcn_mfma_f32_32x32x16_bf16(a, b1, acc[1], 0, 0, 0);
  }

  // C/D: col = lane&31, row = (reg&3) + 8*(reg>>2) + 4*half
#pragma unroll
  for (int j = 0; j < 2; j++) {
    int col = (cg0 + j) * 32 + r;
    int kcd = col >> 4, hd = (col >> 3) & 1, ttd = col & 7;
#pragma unroll
    for (int reg = 0; reg < 16; reg++) {
      int p = mg * 32 + (reg & 3) + 8 * (reg >> 2) + 4 * half;
      if (p < P) {
        int n = b * P + p;
        Ars[((((size_t)(n >> 5)) * 48 + kcd) * 64 + hd * 32 + (n & 31)) * 8 + ttd] =
            f2bfbits(acc[j][reg]);
      }
    }
  }
}

// ---------------------------------------------------------------------------
// Kernel 5a: build hs/ts halves of the head/tail A matrices in fragment order.
// ---------------------------------------------------------------------------
__global__ __launch_bounds__(256) void k_prep_ahs(
    const float* __restrict__ ent_emb, const int* __restrict__ hts,
    short* __restrict__ Ahs, short* __restrict__ Ats, short* __restrict__ Ars) {
  int mg = blockIdx.x, which = blockIdx.y;
  short* Adst = which ? Ats : Ahs;
  int t = threadIdx.x, lane = t & 63, kc0 = t >> 6;
  int rr = lane & 31, half = lane >> 5;
  int row = mg * 32 + rr;
  bool valid = row < N;
  size_t base = 0;
  if (valid) {
    int b = row / P, p = row % P;
    int e = hts[(b * P + p) * 2 + which];
    base = (size_t)(b * E + e) * D;
  }
#pragma unroll
  for (int q = 0; q < 12; q++) {
    int kc = kc0 + q * 4;
    s16x8 v = {0, 0, 0, 0, 0, 0, 0, 0};
    if (valid) {
      const float* p = ent_emb + base + kc * 16 + half * 8;
      float4 v0 = *(const float4*)p;
      float4 v1 = *(const float4*)(p + 4);
      v[0] = f2bfbits(v0.x); v[1] = f2bfbits(v0.y);
      v[2] = f2bfbits(v0.z); v[3] = f2bfbits(v0.w);
      v[4] = f2bfbits(v1.x); v[5] = f2bfbits(v1.y);
      v[6] = f2bfbits(v1.z); v[7] = f2bfbits(v1.w);
    }
    *(s16x8*)(Adst + (((size_t)mg * 48 + kc) * 64 + lane) * 8) = v;
    if (which == 0 && mg == MG - 1) {
      s16x8 z = {0, 0, 0, 0, 0, 0, 0, 0};
      *(s16x8*)(Ars + (((size_t)(MG - 1) * 48 + kc) * 64 + lane) * 8) = z;
    }
  }
}

// ---------------------------------------------------------------------------
// Kernel 5b: pack head_W / tail_W into B-fragment order (bf16) + biases f32.
// ---------------------------------------------------------------------------
struct PrepWSmem { short Ws[16][776]; };

template <bool BF>
static __device__ __forceinline__ void prep_w_body(
    PrepWSmem& sm, const void* headW, const void* headb,
    const void* tailW, const void* tailb,
    short* Wfh, short* Wft, float* bias_h, float* bias_t) {
  int kc = blockIdx.x, which = blockIdx.y;
  const void* W = which ? tailW : headW;
  short* Wf = which ? Wft : Wfh;
  int t = threadIdx.x;
  for (int e = t; e < 16 * EMB; e += 256) {
    int kk = e / EMB, c = e % EMB;
    sm.Ws[kk][c] = f2bfbits(ldf<BF>(W, (size_t)(kc * 16 + kk) * EMB + c));
  }
  __syncthreads();
  int lane = t & 63, cg0 = t >> 6;
  int rr = lane & 31, half = lane >> 5;
#pragma unroll
  for (int q = 0; q < 6; q++) {
    int cg = cg0 + q * 4;
    int col = cg * 32 + rr;
    s16x8 v;
#pragma unroll
    for (int tt = 0; tt < 8; tt++) v[tt] = sm.Ws[half * 8 + tt][col];
    *(s16x8*)(Wf + (((size_t)kc * 24 + cg) * 64 + lane) * 8) = v;
  }
  if (kc == 0) {
    const void* bsrc = which ? tailb : headb;
    float* bdst = which ? bias_t : bias_h;
    for (int c = t; c < EMB; c += 256) bdst[c] = ldf<BF>(bsrc, c);
  }
}

__global__ __launch_bounds__(256) void k_prep_w(
    const void* headW, const void* headb, const void* tailW, const void* tailb,
    short* Wfh, short* Wft, float* bias_h, float* bias_t, const int* flag) {
  __shared__ PrepWSmem sm;
  if (*flag) prep_w_body<true>(sm, headW, headb, tailW, tailb, Wfh, Wft, bias_h, bias_t);
  else       prep_w_body<false>(sm, headW, headb, tailW, tailb, Wfh, Wft, bias_h, bias_t);
}

// ---------------------------------------------------------------------------
// Kernel 5c: hz/tz = tanh(A @ W + bias) via MFMA, output bf16.
// ---------------------------------------------------------------------------
__global__ __launch_bounds__(256) void k_head_mfma(
    const short* __restrict__ Ahs, const short* __restrict__ Ats,
    const short* __restrict__ Ars,
    const short* __restrict__ Wfh, const short* __restrict__ Wft,
    const float* __restrict__ bias_h, const float* __restrict__ bias_t,
    short* __restrict__ hz, short* __restrict__ tz) {
  int mt = blockIdx.x, nt = blockIdx.y, which = blockIdx.z;
  const short* Ahead = which ? Ats : Ahs;
  const short* Wf = which ? Wft : Wfh;
  const float* bias = which ? bias_t : bias_h;
  short* out = which ? tz : hz;

  int t = threadIdx.x, w = t >> 6, lane = t & 63;
  int half = lane >> 5, r = lane & 31;
  int wm = w >> 1, wn = w & 1;
  int mg0 = mt * 4 + wm * 2;
  int cg0 = nt * 4 + wn * 2;

  f32x16 acc[2][2];
#pragma unroll
  for (int i = 0; i < 2; i++)
#pragma unroll
    for (int j = 0; j < 2; j++)
#pragma unroll
      for (int e = 0; e < 16; e++) acc[i][j][e] = 0.f;

#pragma unroll 4
  for (int kc = 0; kc < 48; kc++) {
    s16x8 a0 = *(const s16x8*)(Ahead + (((size_t)(mg0 + 0) * 48 + kc) * 64 + lane) * 8);
    s16x8 a1 = *(const s16x8*)(Ahead + (((size_t)(mg0 + 1) * 48 + kc) * 64 + lane) * 8);
    s16x8 b0 = *(const s16x8*)(Wf + (((size_t)kc * 24 + cg0 + 0) * 64 + lane) * 8);
    s16x8 b1 = *(const s16x8*)(Wf + (((size_t)kc * 24 + cg0 + 1) * 64 + lane) * 8);
    acc[0][0] = __builtin_amdgcn_mfma_f32_32x32x16_bf16(a0, b0, acc[0][0], 0, 0, 0);
    acc[0][1] = __builtin_amdgcn_mfma_f32_32x32x16_bf16(a0, b1, acc[0][1], 0, 0, 0);
    acc[1][0] = __builtin_amdgcn_mfma_f32_32x32x16_bf16(a1, b0, acc[1][0], 0, 0, 0);
    acc[1][1] = __builtin_amdgcn_mfma_f32_32x32x16_bf16(a1, b1, acc[1][1], 0, 0, 0);
  }
#pragma unroll 4
  for (int kc = 0; kc < 48; kc++) {
    s16x8 a0 = *(const s16x8*)(Ars + (((size_t)(mg0 + 0) * 48 + kc) * 64 + lane) * 8);
    s16x8 a1 = *(const s16x8*)(Ars + (((size_t)(mg0 + 1) * 48 + kc) * 64 + lane) * 8);
    s16x8 b0 = *(const s16x8*)(Wf + (((size_t)(kc + 48) * 24 + cg0 + 0) * 64 + lane) * 8);
    s16x8 b1 = *(const s16x8*)(Wf + (((size_t)(kc + 48) * 24 + cg0 + 1) * 64 + lane) * 8);
    acc[0][0] = __builtin_amdgcn_mfma_f32_32x32x16_bf16(a0, b0, acc[0][0], 0, 0, 0);
    acc[0][1] = __builtin_amdgcn_mfma_f32_32x32x16_bf16(a0, b1, acc[0][1], 0, 0, 0);
    acc[1][0] = __builtin_amdgcn_mfma_f32_32x32x16_bf16(a1, b0, acc[1][0], 0, 0, 0);
    acc[1][1] = __builtin_amdgcn_mfma_f32_32x32x16_bf16(a1, b1, acc[1][1], 0, 0, 0);
  }

#pragma unroll
  for (int i = 0; i < 2; i++) {
    int rowbase = (mg0 + i) * 32 + 4 * half;
#pragma unroll
    for (int j = 0; j < 2; j++) {
      int col = (cg0 + j) * 32 + r;
      float bv = bias[col];
#pragma unroll
      for (int reg = 0; reg < 16; reg++) {
        int n = rowbase + (reg & 3) + 8 * (reg >> 2);
        if (n < N) out[(size_t)n * EMB + col] = f2bfbits(tanhf(acc[i][j][reg] + bv));
      }
    }
  }
}

// ---------------------------------------------------------------------------
// Kernel 6a: pre-pack bil_W into MFMA B-fragment order, bf16.
// ---------------------------------------------------------------------------
struct TwSmem { float Ws[16][100]; };

template <bool BF>
static __device__ __forceinline__ void transpose_w_body(
    TwSmem& sm, const void* bilW, short* Wt) {
  int s16i = blockIdx.x, kb = blockIdx.y;
  int t = threadIdx.x;
  size_t kbase = (size_t)kb * 4096 + s16i * 16;
  for (int e = t; e < 16 * NL; e += 256) {
    int rr = e / NL, l = e % NL;
    sm.Ws[rr][l] = ldf<BF>(bilW, (kbase + rr) * NL + l);
  }
  __syncthreads();
  int c = t >> 6, lane = t & 63;
  int half = lane >> 5, col = lane & 31;
  int label = c * 32 + col;
  s16x8 v;
#pragma unroll
  for (int tt = 0; tt < 8; tt++) {
    float x = (label < NL) ? sm.Ws[half * 8 + tt][label] : 0.f;
    v[tt] = f2bfbits(x);
  }
  size_t off = ((((size_t)kb * 256 + s16i) * 4 + c) * 64 + lane) * 8;
  *(s16x8*)(Wt + off) = v;
}

__global__ __launch_bounds__(256) void k_transpose_w(
    const void* bilW, short* Wt, const int* flag) {
  __shared__ TwSmem sm;
  if (*flag) transpose_w_body<true>(sm, bilW, Wt);
  else       transpose_w_body<false>(sm, bilW, Wt);
}

// ---------------------------------------------------------------------------
// Kernel 6b: zero logits accumulator
// ---------------------------------------------------------------------------
__global__ __launch_bounds__(256) void k_zero_logits(float* __restrict__ logits_f) {
  int idx = blockIdx.x * 256 + threadIdx.x;
  if (idx < N * NL) logits_f[idx] = 0.f;
}

// ---------------------------------------------------------------------------
// Kernel 6c: bilinear logits via MFMA 32x32x16 bf16, A generated on the fly.
// i-loop split across blockIdx.z (2 halves of 32) for 456 blocks -> 2 blk/CU.
// ---------------------------------------------------------------------------
__global__ __launch_bounds__(256) void k_logits_mfma(
    const short* __restrict__ hz, const short* __restrict__ tz,
    const short* __restrict__ Wt, float* __restrict__ logits_f) {
  int kb = blockIdx.x;
  int mb = blockIdx.y;
  int z = blockIdx.z;  // i-half
  int t = threadIdx.x;
  int w = t >> 6, lane = t & 63;
  int half = lane >> 5, r = lane & 31;
  int nb = mb * 128;

  __shared__ float hzs[128][33];
  {
    int row = t >> 1;
    int col0 = (t & 1) * 16;
    int n = nb + row;
#pragma unroll
    for (int q = 0; q < 2; q++) {
      float vv[8] = {0.f, 0.f, 0.f, 0.f, 0.f, 0.f, 0.f, 0.f};
      if (n < N) {
        s16x8 v = *(const s16x8*)(hz + (size_t)n * EMB + kb * 64 + z * 32 + col0 + q * 8);
#pragma unroll
        for (int tt = 0; tt < 8; tt++) vv[tt] = bf2f(v[tt]);
      }
#pragma unroll
      for (int tt = 0; tt < 8; tt++) hzs[row][col0 + q * 8 + tt] = vv[tt];
    }
  }
  float tzr[4][8];
  {
    int n = nb + w * 32 + r;
#pragma unroll
    for (int q4 = 0; q4 < 4; q4++) {
      s16x8 v = {0, 0, 0, 0, 0, 0, 0, 0};
      if (n < N) v = *(const s16x8*)(tz + (size_t)n * EMB + kb * 64 + q4 * 16 + half * 8);
#pragma unroll
      for (int tt = 0; tt < 8; tt++) tzr[q4][tt] = bf2f(v[tt]);
    }
  }
  __syncthreads();

  f32x16 acc[4];
#pragma unroll
  for (int c = 0; c < 4; c++)
#pragma unroll
    for (int e = 0; e < 16; e++) acc[c][e] = 0.f;

  const int wrow = w * 32 + r;
  const short* wbase = Wt + (((size_t)kb * 256) * 4) * 64 * 8 + (size_t)lane * 8;

#pragma unroll 2
  for (int ii = 0; ii < 32; ii++) {
    int i = z * 32 + ii;
    float hv = hzs[wrow][ii];
#pragma unroll
    for (int q4 = 0; q4 < 4; q4++) {
      s16x8 af;
#pragma unroll
      for (int tt = 0; tt < 8; tt++) af[tt] = f2bfbits(hv * tzr[q4][tt]);
      int s16i = i * 4 + q4;
#pragma unroll
      for (int c = 0; c < 4; c++) {
        s16x8 bf = *(const s16x8*)(wbase + ((size_t)s16i * 4 + c) * 64 * 8);
        acc[c] = __builtin_amdgcn_mfma_f32_32x32x16_bf16(af, bf, acc[c], 0, 0, 0);
      }
    }
  }

#pragma unroll
  for (int c = 0; c < 4; c++) {
    int label = c * 32 + r;
    if (label < NL) {
#pragma unroll
      for (int reg = 0; reg < 16; reg++) {
        int row = (reg & 3) + 8 * (reg >> 2) + 4 * half;
        int n = nb + w * 32 + row;
        if (n < N) atomicAdd(&logits_f[(size_t)n * NL + label], acc[c][reg]);
      }
    }
  }
}

// ---------------------------------------------------------------------------
// Kernel 6d: logits += bias; emit output logits in out dtype
// ---------------------------------------------------------------------------
template <bool BF>
static __device__ __forceinline__ void finish_body(
    float* logits_f, const void* bilb, void* out) {
  int idx = blockIdx.x * 256 + threadIdx.x;
  if (idx >= N * NL) return;
  int l = idx % NL;
  float s = logits_f[idx] + ldf<BF>(bilb, l);
  logits_f[idx] = s;
  stf<BF>(out, (size_t)idx + 1, s);  // out[0] = risk, out[1..] = logits
}

__global__ __launch_bounds__(256) void k_finish(
    float* logits_f, const void* bilb, void* out, const int* flag) {
  if (*flag) finish_body<true>(logits_f, bilb, out);
  else       finish_body<false>(logits_f, bilb, out);
}

// ---------------------------------------------------------------------------
// Kernel 7: per-relation PU risk. grid = RELS blocks.
// ---------------------------------------------------------------------------
struct RiskSmem { float red[5][256]; };

template <bool BF>
static __device__ __forceinline__ void risk_body(
    RiskSmem& sm, const float* logits_f, const int* labels,
    const void* priors_l, const void* priors_o, float* riskarr) {
  int r = blockIdx.x;  // 0..95
  int t = threadIdx.x;
  float s_neg = 0.f, s_pp = 0.f, s_pn = 0.f, c_neg = 0.f, c_pos = 0.f;
  for (int n = t; n < N; n += 256) {
    float sc = logits_f[(size_t)n * NL + (r + 1)] - logits_f[(size_t)n * NL];
    bool pos = labels[(size_t)n * NL + (r + 1)] == 1;
    float ln = 0.25f * (sc + 1.f) * (sc + 1.f);  // sign=-1
    float lp = 0.25f * (sc - 1.f) * (sc - 1.f);  // sign=+1
    if (pos) { c_pos += 1.f; s_pp += lp; s_pn += ln; }
    else     { c_neg += 1.f; s_neg += ln; }
  }
  sm.red[0][t] = s_neg; sm.red[1][t] = s_pp; sm.red[2][t] = s_pn;
  sm.red[3][t] = c_neg; sm.red[4][t] = c_pos;
  __syncthreads();
  for (int off = 128; off > 0; off >>= 1) {
    if (t < off) {
#pragma unroll
      for (int q = 0; q < 5; q++) sm.red[q][t] += sm.red[q][t + off];
    }
    __syncthreads();
  }
  if (t == 0) {
    float sq_neg   = sm.red[3][0] > 0.f ? sm.red[0][0] / fmaxf(sm.red[3][0], 1.f) : 0.f;
    float sq_pos_p = sm.red[4][0] > 0.f ? sm.red[1][0] / fmaxf(sm.red[4][0], 1.f) : 0.f;
    float sq_pos_n = sm.red[4][0] > 0.f ? sm.red[2][0] / fmaxf(sm.red[4][0], 1.f) : 0.f;
    float po = ldf<BF>(priors_o, r), pl = ldf<BF>(priors_l, r);
    float weight = sqrtf((1.f - po) / po);
    float pu = (po - pl) / (1.f - pl);
    float risk1 = (1.f - po) / (1.f - pu) * sq_neg - (pu - pu * po) / (1.f - pu) * sq_pos_n;
    float risk2 = po * sq_pos_p * weight;
    riskarr[r] = (risk1 < 0.f) ? -risk1 : (risk1 + risk2);  // BETA=0, GAMMA=1
  }
}

__global__ __launch_bounds__(256) void k_risk(
    const float* logits_f, const int* labels, const void* priors_l,
    const void* priors_o, float* riskarr, const int* flag) {
  __shared__ RiskSmem sm;
  if (*flag) risk_body<true>(sm, logits_f, labels, priors_l, priors_o, riskarr);
  else       risk_body<false>(sm, logits_f, labels, priors_l, priors_o, riskarr);
}

__global__ __launch_bounds__(128) void k_risk_sum(
    const float* __restrict__ riskarr, void* out, const int* flag) {
  __shared__ float red[128];
  int t = threadIdx.x;
  red[t] = (t < RELS) ? riskarr[t] : 0.f;
  __syncthreads();
  for (int off = 64; off > 0; off >>= 1) {
    if (t < off) red[t] += red[t + off];
    __syncthreads();
  }
  if (t == 0) {
    if (*flag) stf<true>(out, 0, red[0]);
    else       stf<false>(out, 0, red[0]);
  }
}

// ---------------------------------------------------------------------------
extern "C" void kernel_launch(void* const* d_in, const int* in_sizes, int n_in,
                              void* d_out, int out_size, void* d_ws, size_t ws_size,
                              hipStream_t stream) {
  const void* seq    = d_in[0];
  const void* att    = d_in[1];
  const int*  midx   = (const int*)d_in[2];
  const void* mmask  = d_in[3];
  const int*  hts    = (const int*)d_in[4];
  const int*  labels = (const int*)d_in[5];
  const void* pl     = d_in[6];
  const void* po     = d_in[7];
  const void* headW  = d_in[8];
  const void* headb  = d_in[9];
  const void* tailW  = d_in[10];
  const void* tailb  = d_in[11];
  const void* bilW   = d_in[12];
  const void* bilb   = d_in[13];

  // Workspace layout (floats after 64B flag); ~38.3 MB total.
  // regionA = [ent_att(bf16) | Aht | Sf]:
  //   ent_att dead after k_ht_att; Aht/Sf dead after k_rs_mfma.
  //   Ars aliases regionA start (after ent_att dead);
  //   Wt  aliases regionA start (after k_head_mfma, all regionA dead).
  int* flag = (int*)d_ws;
  float* w = (float*)d_ws + 16;
  float* ent_emb  = w;                                   //    92,160 f
  short* hz       = (short*)(ent_emb + (size_t)B * E * D); // 1,843,200 s
  short* tz       = hz + (size_t)N * EMB;                // 1,843,200 s
  float* logits_f = (float*)(tz + (size_t)N * EMB);      //   232,800 f
  float* riskarr  = logits_f + (size_t)N * NL;           //       128 f
  float* bias_h   = riskarr + 128;                       //       768 f
  float* bias_t   = bias_h + 768;                        //       768 f
  float* regionA  = bias_t + 768;                        // 4,358,144 f
  short* ent_att  = (short*)regionA;                     // 1,474,560 s (bf16)
  short* Aht      = (short*)(regionA + 1474560);         // 2,621,440 s
  short* Sf       = Aht + (size_t)B * MGB * 64 * 512;    // 3,145,728 s
  short* Ars      = (short*)regionA;                     // 1,867,776 s (alias)
  short* Wt       = (short*)regionA;                     // 6,291,456 s (alias, late)
  float* after    = regionA + 4358144;
  short* Ahs      = (short*)after;                       // 1,867,776 s
  short* Ats      = Ahs + (size_t)MG * 48 * 512;         // 1,867,776 s
  short* Wfh      = Ats + (size_t)MG * 48 * 512;         // 1,179,648 s
  short* Wft      = Wfh + (size_t)96 * 24 * 512;         // 1,179,648 s

  k_detect<<<1, 256, 0, stream>>>((const unsigned int*)mmask, flag);
  k_ent_emb<<<B * E, 256, 0, stream>>>(seq, midx, mmask, ent_emb, flag);
  k_ent_att<<<B * E * H, 256, 0, stream>>>(att, midx, mmask, ent_att, flag);
  k_ht_att<<<B * P, 256, 0, stream>>>(ent_att, hts, Aht);
  k_prep_seq<<<dim3(64, B), 256, 0, stream>>>(seq, Sf, Aht, flag);
  k_rs_mfma<<<dim3(10, 6, B), 256, 0, stream>>>(Aht, Sf, Ars);
  k_prep_ahs<<<dim3(MG, 2), 256, 0, stream>>>(ent_emb, hts, Ahs, Ats, Ars);
  k_prep_w<<<dim3(96, 2), 256, 0, stream>>>(headW, headb, tailW, tailb,
                                            Wfh, Wft, bias_h, bias_t, flag);
  k_head_mfma<<<dim3(19, 6, 2), 256, 0, stream>>>(Ahs, Ats, Ars, Wfh, Wft,
                                                  bias_h, bias_t, hz, tz);
  k_transpose_w<<<dim3(256, 12), 256, 0, stream>>>(bilW, Wt, flag);
  k_zero_logits<<<(N * NL + 255) / 256, 256, 0, stream>>>(logits_f);
  k_logits_mfma<<<dim3(12, (N + 127) / 128, 2), 256, 0, stream>>>(hz, tz, Wt, logits_f);
  k_finish<<<(N * NL + 255) / 256, 256, 0, stream>>>(logits_f, bilb, d_out, flag);
  k_risk<<<RELS, 256, 0, stream>>>(logits_f, labels, pl, po, riskarr, flag);
  k_risk_sum<<<1, 128, 0, stream>>>(riskarr, d_out, flag);
}